// Round 2
// baseline (1717.250 us; speedup 1.0000x reference)
//
#include <hip/hip_runtime.h>
#include <cmath>

// ---------------------------------------------------------------------------
// SemanticFreeFuXiBlock on MI355X (gfx950), bf16 MFMA implementation.
// B=64, N=1024, D=512, H=8, LD=64, HIDDEN=2048, NB=128, T = in_sizes[0]/512.
// NOTE: integer inputs (x_offsets, all_timestamps) arrive as int32 per the
// harness contract ("integer -> const int*").
// ---------------------------------------------------------------------------

using u16 = unsigned short;

typedef __bf16 bf16x8 __attribute__((ext_vector_type(8)));
typedef float  f32x4  __attribute__((ext_vector_type(4)));

#define TS_SCALE_F (float)(128.0 / 14.0)

__device__ __forceinline__ u16 f2b(float f) {            // RNE f32 -> bf16 bits
  unsigned u = __float_as_uint(f);
  unsigned r = 0x7FFFu + ((u >> 16) & 1u);
  return (u16)((u + r) >> 16);
}
__device__ __forceinline__ float b2f(u16 v) {
  return __uint_as_float(((unsigned)v) << 16);
}
__device__ __forceinline__ bf16x8 as_frag(uint4 r) {
  union { uint4 u; bf16x8 v; } c; c.u = r; return c.v;
}

// ---------------------------------------------------------------------------
// Generic bf16 GEMM: C(MxN) = epilogue(A(MxK) @ W(KxN)).
// Tile 128x128x32, 256 threads = 4 waves (2x2 of 64x64), mfma_f32_16x16x32_bf16.
// lA: [128][40] u16 (pad 40 -> 2-way bank alias = free).
// lB: transposed+XOR-swizzled: elem(k,c) at byte (k>>3)*2048 + c*16 + (k&7)*2,
//     byte ^= ((c>>3)&7)<<4  (keeps ds_read_b128 16B-contiguous, spreads banks).
// ---------------------------------------------------------------------------
#define EPI_SILU_BF16 0
#define EPI_ADD_F32   1

template <int EPI>
__global__ __launch_bounds__(256, 2) void gemm_bf16(
    const u16* __restrict__ A, const u16* __restrict__ W,
    void* __restrict__ C, const float* __restrict__ ADD,
    int M, int N, int K)
{
  __shared__ u16 lA[128 * 40];
  __shared__ u16 lB[4096];

  const int tid  = threadIdx.x;
  const int t0   = blockIdx.x * 128;
  const int c0   = blockIdx.y * 128;
  const int wave = tid >> 6, lane = tid & 63;
  const int wr   = (wave >> 1) * 64, wc = (wave & 1) * 64;
  const int l15  = lane & 15, l4 = lane >> 4;

  f32x4 z = {0.f, 0.f, 0.f, 0.f};
  f32x4 acc[4][4];
#pragma unroll
  for (int m = 0; m < 4; ++m)
#pragma unroll
    for (int j = 0; j < 4; ++j) acc[m][j] = z;

  const int ar = tid >> 1, ak = (tid & 1) * 16;      // A stage: 16 bf16 along K
  const int bk = tid >> 3, bc = (tid & 7) * 16;      // B stage: 16 bf16 along N
  const bool arow_ok = (t0 + ar) < M;
  const u16* aptr = A + (size_t)(t0 + ar) * K + ak;
  const u16* wptr = W + (size_t)bk * N + c0 + bc;

  for (int k0 = 0; k0 < K; k0 += 32) {
    uint4 a0 = make_uint4(0, 0, 0, 0), a1 = a0;
    if (arow_ok) {
      a0 = *(const uint4*)(aptr + k0);
      a1 = *(const uint4*)(aptr + k0 + 8);
    }
    uint4 w0 = *(const uint4*)(wptr + (size_t)k0 * N);
    uint4 w1v = *(const uint4*)(wptr + (size_t)k0 * N + 8);

    *(uint4*)&lA[ar * 40 + ak]     = a0;
    *(uint4*)&lA[ar * 40 + ak + 8] = a1;
    {
      u16 tmp[16];
      *(uint4*)tmp       = w0;
      *(uint4*)(tmp + 8) = w1v;
      const int kb = bk >> 3, ke = bk & 7;
      char* base = (char*)lB;
#pragma unroll
      for (int i = 0; i < 16; ++i) {
        int col = bc + i;
        int off = (kb * 2048 + col * 16 + ke * 2) ^ (((col >> 3) & 7) << 4);
        *(u16*)(base + off) = tmp[i];
      }
    }
    __syncthreads();

    bf16x8 af[4], bfv[4];
#pragma unroll
    for (int m = 0; m < 4; ++m)
      af[m] = as_frag(*(const uint4*)&lA[(wr + m * 16 + l15) * 40 + l4 * 8]);
#pragma unroll
    for (int j = 0; j < 4; ++j) {
      int col = wc + j * 16 + l15;
      int off = (l4 * 2048 + col * 16) ^ (((col >> 3) & 7) << 4);
      bfv[j] = as_frag(*(const uint4*)((char*)lB + off));
    }
#pragma unroll
    for (int m = 0; m < 4; ++m)
#pragma unroll
      for (int j = 0; j < 4; ++j)
        acc[m][j] = __builtin_amdgcn_mfma_f32_16x16x32_bf16(af[m], bfv[j], acc[m][j], 0, 0, 0);
    __syncthreads();
  }

#pragma unroll
  for (int m = 0; m < 4; ++m) {
#pragma unroll
    for (int r = 0; r < 4; ++r) {
      int row = t0 + wr + m * 16 + l4 * 4 + r;
      if (row >= M) continue;
#pragma unroll
      for (int j = 0; j < 4; ++j) {
        int col = c0 + wc + j * 16 + l15;
        size_t idx = (size_t)row * N + col;
        float y = acc[m][j][r];
        if constexpr (EPI == EPI_SILU_BF16) {
          float s = y / (1.f + __expf(-y));          // silu
          ((u16*)C)[idx] = f2b(s);
        } else {
          ((float*)C)[idx] = y + ADD[idx];
        }
      }
    }
  }
}

// ---------------------------------------------------------------------------
// Fused dual attention: for batch b, row-tile nt (128 rows), hd-col-tile ct
// (128 of 512), compute out_pos and out_ts over causal m<=n, ragged len_b.
// Scores generated on the fly into LDS (bf16); V gathered from proj cols
// [1024,1536) with rows >= len zeroed. Output written bf16 with the head-
// interleaved layout of concat([out_pos,out_ts],-1).reshape(.,1024).
// ---------------------------------------------------------------------------
__global__ __launch_bounds__(256, 1) void attn_fused(
    const u16* __restrict__ proj,      // T x 1536 bf16
    const int* __restrict__ xoff,      // B+1 (int32)
    const int* __restrict__ tstamp,    // B x 1024 (int32)
    const float* __restrict__ pos_w,   // 2047
    const float* __restrict__ ts_w,    // 129
    u16* __restrict__ attn_out,        // T x 1024 bf16
    int Ttot)
{
  const int blk = blockIdx.x;
  const int b  = blk >> 5;
  const int nt = (blk >> 2) & 7;
  const int ct = blk & 3;
  const int off = xoff[b];
  int len = xoff[b + 1] - off;
  if (len < 0) len = 0;
  if (len > 1024) len = 1024;
  if (off < 0 || off + len > Ttot) return;   // hardening vs corrupt offsets
  const int n0 = nt * 128;
  if (n0 >= len) return;
  const int c0 = ct * 128;

  __shared__ u16 sSp[128 * 40];
  __shared__ u16 sSt[128 * 40];
  __shared__ u16 sV[4096];
  __shared__ float s_tsw[132];

  const int tid = threadIdx.x;
  if (tid < 129) s_tsw[tid] = ts_w[tid];
  __syncthreads();

  const int wave = tid >> 6, lane = tid & 63;
  const int wr = (wave >> 1) * 64, wc = (wave & 1) * 64;
  const int l15 = lane & 15, l4 = lane >> 4;

  const int sn    = tid >> 1;          // score row this thread fills
  const int n_abs = n0 + sn;           // always < 1024
  const int t_n   = tstamp[b * 1024 + n_abs];

  const int mEnd = (n0 + 128 < len) ? (n0 + 128) : len;

  f32x4 z = {0.f, 0.f, 0.f, 0.f};
  f32x4 accP[4][4], accT[4][4];
#pragma unroll
  for (int m = 0; m < 4; ++m)
#pragma unroll
    for (int j = 0; j < 4; ++j) { accP[m][j] = z; accT[m][j] = z; }

  const int vk = tid >> 3, vc = (tid & 7) * 16;

  for (int m0 = 0; m0 < mEnd; m0 += 32) {
    // ---- stage V tile (32 x 128), transposed+swizzled, ragged-zeroed ----
    {
      int mm = m0 + vk;
      uint4 v0 = make_uint4(0, 0, 0, 0), v1 = v0;
      if (mm < len) {
        const u16* src = proj + (size_t)(off + mm) * 1536 + 1024 + c0 + vc;
        v0 = *(const uint4*)src;
        v1 = *(const uint4*)(src + 8);
      }
      u16 tmp[16];
      *(uint4*)tmp       = v0;
      *(uint4*)(tmp + 8) = v1;
      const int kb = vk >> 3, ke = vk & 7;
#pragma unroll
      for (int i = 0; i < 16; ++i) {
        int col = vc + i;
        int o2 = (kb * 2048 + col * 16 + ke * 2) ^ (((col >> 3) & 7) << 4);
        *(u16*)((char*)sV + o2) = tmp[i];
      }
    }
    // ---- generate score tiles (128 x 32) for pos and ts ----
    {
      const int msb = m0 + (tid & 1) * 16;
      u16 tp[16], tt[16];
#pragma unroll
      for (int i = 0; i < 16; ++i) {
        int mm = msb + i;
        float sp = 0.f, st = 0.f;
        if (mm <= n_abs) {
          sp = pos_w[n_abs - mm + 1023];
          int d = t_n - tstamp[b * 1024 + mm];
          if (d < 0) d = -d;
          float dt = (float)d;
          int bkt = (int)floorf(log1pf(dt) * TS_SCALE_F);
          bkt = bkt < 0 ? 0 : (bkt > 128 ? 128 : bkt);
          st = s_tsw[bkt];
        }
        tp[i] = f2b(sp);
        tt[i] = f2b(st);
      }
      int wb = sn * 40 + (tid & 1) * 16;
      *(uint4*)&sSp[wb]     = *(uint4*)tp;
      *(uint4*)&sSp[wb + 8] = *(uint4*)(tp + 8);
      *(uint4*)&sSt[wb]     = *(uint4*)tt;
      *(uint4*)&sSt[wb + 8] = *(uint4*)(tt + 8);
    }
    __syncthreads();

    bf16x8 ap[4], at[4], bv[4];
#pragma unroll
    for (int m = 0; m < 4; ++m) {
      ap[m] = as_frag(*(const uint4*)&sSp[(wr + m * 16 + l15) * 40 + l4 * 8]);
      at[m] = as_frag(*(const uint4*)&sSt[(wr + m * 16 + l15) * 40 + l4 * 8]);
    }
#pragma unroll
    for (int j = 0; j < 4; ++j) {
      int col = wc + j * 16 + l15;
      int o2 = (l4 * 2048 + col * 16) ^ (((col >> 3) & 7) << 4);
      bv[j] = as_frag(*(const uint4*)((char*)sV + o2));
    }
#pragma unroll
    for (int m = 0; m < 4; ++m)
#pragma unroll
      for (int j = 0; j < 4; ++j) {
        accP[m][j] = __builtin_amdgcn_mfma_f32_16x16x32_bf16(ap[m], bv[j], accP[m][j], 0, 0, 0);
        accT[m][j] = __builtin_amdgcn_mfma_f32_16x16x32_bf16(at[m], bv[j], accT[m][j], 0, 0, 0);
      }
    __syncthreads();
  }

  // ---- store bf16 with head-interleaved combined layout ----
#pragma unroll
  for (int m = 0; m < 4; ++m)
#pragma unroll
    for (int r = 0; r < 4; ++r) {
      int n = n0 + wr + m * 16 + l4 * 4 + r;
      if (n >= len) continue;
      size_t t = (size_t)(off + n);
#pragma unroll
      for (int j = 0; j < 4; ++j) {
        int hd = c0 + wc + j * 16 + l15;            // 0..511
        int colP = ((hd >> 6) << 7) + (hd & 63);    // h*128 + d
        attn_out[t * 1024 + colP]      = f2b(accP[m][j][r]);
        attn_out[t * 1024 + colP + 64] = f2b(accT[m][j][r]);
      }
    }
}

// ---------------------------------------------------------------------------
// Row-wise RMS norm prep: out_bf16[row] = rmsnorm(in[row]) (* mul[row] opt.)
// One 256-thread block per row. INBF: input is bf16 (u16) instead of f32.
// Supports in-place (out == in) when INBF: each thread re-reads its own
// element before overwriting it.
// ---------------------------------------------------------------------------
template <int D, bool HASMUL, bool INBF>
__global__ __launch_bounds__(256) void rms_prep(
    const void* __restrict__ in_, const u16* __restrict__ mul, int mulStride,
    u16* __restrict__ out)
{
  const int row = blockIdx.x;
  const int tid = threadIdx.x;
  const float* rf = (const float*)in_ + (INBF ? 0 : (size_t)row * D);
  const u16*   rb = (const u16*)in_ + (INBF ? (size_t)row * D : 0);
  float ss = 0.f;
#pragma unroll
  for (int i = tid; i < D; i += 256) {
    float v = INBF ? b2f(rb[i]) : rf[i];
    ss += v * v;
  }
#pragma unroll
  for (int o = 32; o > 0; o >>= 1) ss += __shfl_down(ss, o, 64);
  __shared__ float sred[4];
  const int wave = tid >> 6, lane = tid & 63;
  if (lane == 0) sred[wave] = ss;
  __syncthreads();
  float inv = rsqrtf((sred[0] + sred[1] + sred[2] + sred[3]) / (float)D + 1e-6f);
#pragma unroll
  for (int i = tid; i < D; i += 256) {
    float v = (INBF ? b2f(rb[i]) : rf[i]) * inv;
    if constexpr (HASMUL) v *= b2f(mul[(size_t)row * mulStride + i]);
    out[(size_t)row * D + i] = f2b(v);
  }
}

__global__ void cvt_bf16(const float* __restrict__ in, u16* __restrict__ out, int n) {
  int i = blockIdx.x * 256 + threadIdx.x;
  if (i < n) out[i] = f2b(in[i]);
}

// ---------------------------------------------------------------------------
extern "C" void kernel_launch(void* const* d_in, const int* in_sizes, int n_in,
                              void* d_out, int out_size, void* d_ws, size_t ws_size,
                              hipStream_t stream)
{
  const float* x      = (const float*)d_in[0];
  const int*   xoff   = (const int*)d_in[1];    // int32 per harness contract
  const int*   tstamp = (const int*)d_in[2];    // int32 per harness contract
  // d_in[3] = invalid_attn_mask (tril) -- implied by causal masking, unused
  const float* uv     = (const float*)d_in[4];
  const float* pos_w  = (const float*)d_in[5];
  const float* ts_w   = (const float*)d_in[6];
  const float* w_ams  = (const float*)d_in[7];
  const float* w1     = (const float*)d_in[8];
  const float* w2     = (const float*)d_in[9];
  const int T = in_sizes[0] / 512;

  char* ws = (char*)d_ws;
  size_t o = 0;
  auto take = [&](size_t bytes) { size_t r = o; o += (bytes + 255) & ~(size_t)255; return r; };

  u16* uvb    = (u16*)(ws + take((size_t)512 * 1536 * 2));
  u16* wamsb  = (u16*)(ws + take((size_t)1024 * 512 * 2));
  u16* w1b    = (u16*)(ws + take((size_t)512 * 2048 * 2));
  u16* w2b    = (u16*)(ws + take((size_t)2048 * 512 * 2));
  u16* A1     = (u16*)(ws + take((size_t)T * 512 * 2));   // rmsnorm(x); later rmsnorm(h)
  size_t o_proj = take((size_t)T * 1536 * 2);
  u16* proj   = (u16*)(ws + o_proj);                      // silu proj bf16 (u|v)
  u16* attn   = (u16*)(ws + take((size_t)T * 1024 * 2));  // attn bf16; A2 in-place
  u16* mid    = (u16*)(ws + o_proj);                      // T x 2048 bf16, aliases
                                                          // dead proj+attn (5120B/row
                                                          // available >= 4096B/row)
  float* h    = (float*)d_out;                            // h lives in d_out

  // If the workspace is too small, launch nothing: bench reports a clean
  // absmax failure (diagnostic) instead of an OOB fault.
  if (ws_size < o) return;

  // weight conversions f32 -> bf16
  cvt_bf16<<<(512 * 1536 + 255) / 256, 256, 0, stream>>>(uv, uvb, 512 * 1536);
  cvt_bf16<<<(1024 * 512 + 255) / 256, 256, 0, stream>>>(w_ams, wamsb, 1024 * 512);
  cvt_bf16<<<(512 * 2048 + 255) / 256, 256, 0, stream>>>(w1, w1b, 512 * 2048);
  cvt_bf16<<<(2048 * 512 + 255) / 256, 256, 0, stream>>>(w2, w2b, 2048 * 512);

  // A1 = bf16(rmsnorm(x))
  rms_prep<512, false, false><<<T, 256, 0, stream>>>(x, nullptr, 0, A1);

  // proj = silu(A1 @ uv)   (T x 1536)
  dim3 g1((T + 127) / 128, 12);
  gemm_bf16<EPI_SILU_BF16><<<g1, 256, 0, stream>>>(A1, uvb, proj, nullptr, T, 1536, 512);

  // attention -> attn (T x 1024 bf16, head-interleaved pos/ts)
  attn_fused<<<64 * 32, 256, 0, stream>>>(proj, xoff, tstamp, pos_w, ts_w, attn, T);

  // A2 = bf16(u * rmsnorm(attn)), in-place over attn
  rms_prep<1024, true, true><<<T, 256, 0, stream>>>(attn, proj, 1536, attn);

  // h = x + A2 @ w_ams   (T x 512) -> d_out
  dim3 g3((T + 127) / 128, 4);
  gemm_bf16<EPI_ADD_F32><<<g3, 256, 0, stream>>>(attn, wamsb, h, x, T, 512, 1024);

  // A3 = bf16(rmsnorm(h)) -> reuse A1 buffer
  rms_prep<512, false, false><<<T, 256, 0, stream>>>(h, nullptr, 0, A1);

  // mid = silu(A3 @ w1)   (T x 2048), aliases dead proj+attn
  dim3 g4((T + 127) / 128, 16);
  gemm_bf16<EPI_SILU_BF16><<<g4, 256, 0, stream>>>(A1, w1b, mid, nullptr, T, 2048, 512);

  // out = h + mid @ w2    (T x 512), in-place on d_out
  dim3 g5((T + 127) / 128, 4);
  gemm_bf16<EPI_ADD_F32><<<g5, 256, 0, stream>>>(mid, w2b, h, h, T, 512, 2048);
}

// Round 4
// 983.029 us; speedup vs baseline: 1.7469x; 1.7469x over previous
//
#include <hip/hip_runtime.h>
#include <cmath>

// ---------------------------------------------------------------------------
// SemanticFreeFuXiBlock on MI355X (gfx950), bf16 MFMA implementation.
// B=64, N=1024, D=512, H=8, LD=64, HIDDEN=2048, NB=128, T = in_sizes[0]/512.
// Round 4: round-3 design (precomputed score panels, attention as pure dual
// GEMM) with workspace shrunk to ~219 MB via region time-multiplexing:
//   S2 region: A1 -> tsS -> A2 -> mid(head)   (disjoint lifetimes)
//   d_out:     attn bf16 scratch -> h (f32)
//   proj tail: A1' = rmsnorm(h)
// ---------------------------------------------------------------------------

using u16 = unsigned short;

typedef __bf16 bf16x8 __attribute__((ext_vector_type(8)));
typedef float  f32x4  __attribute__((ext_vector_type(4)));

#define TS_SCALE_F (float)(128.0 / 14.0)

__device__ __forceinline__ u16 f2b(float f) {            // RNE f32 -> bf16 bits
  unsigned u = __float_as_uint(f);
  unsigned r = 0x7FFFu + ((u >> 16) & 1u);
  return (u16)((u + r) >> 16);
}
__device__ __forceinline__ float b2f(u16 v) {
  return __uint_as_float(((unsigned)v) << 16);
}
__device__ __forceinline__ bf16x8 as_frag(uint4 r) {
  union { uint4 u; bf16x8 v; } c; c.u = r; return c.v;
}

// ts_s panel base (elements): per batch 36*16384 elems; per nt prefix
// 16384 * nt*(nt+1)/2; panel (b,nt) is 128 rows x W cols, W = 128*(nt+1).
__device__ __forceinline__ size_t ts_base_elems(int b, int nt) {
  return (size_t)b * 589824 + (size_t)(nt * (nt + 1) / 2) * 16384;
}

// ---------------------------------------------------------------------------
// Generic bf16 GEMM: C(MxN) = epilogue(A(MxK) @ W(KxN)).
// Tile 128x128x32, 256 threads = 4 waves (2x2 of 64x64), mfma_f32_16x16x32_bf16.
// ---------------------------------------------------------------------------
#define EPI_SILU_BF16 0
#define EPI_ADD_F32   1

template <int EPI>
__global__ __launch_bounds__(256, 2) void gemm_bf16(
    const u16* __restrict__ A, const u16* __restrict__ W,
    void* __restrict__ C, const float* __restrict__ ADD,
    int M, int N, int K)
{
  __shared__ u16 lA[128 * 40];
  __shared__ u16 lB[4096];

  const int tid  = threadIdx.x;
  const int t0   = blockIdx.x * 128;
  const int c0   = blockIdx.y * 128;
  const int wave = tid >> 6, lane = tid & 63;
  const int wr   = (wave >> 1) * 64, wc = (wave & 1) * 64;
  const int l15  = lane & 15, l4 = lane >> 4;

  f32x4 z = {0.f, 0.f, 0.f, 0.f};
  f32x4 acc[4][4];
#pragma unroll
  for (int m = 0; m < 4; ++m)
#pragma unroll
    for (int j = 0; j < 4; ++j) acc[m][j] = z;

  const int ar = tid >> 1, ak = (tid & 1) * 16;
  const int bk = tid >> 3, bc = (tid & 7) * 16;
  const bool arow_ok = (t0 + ar) < M;
  const u16* aptr = A + (size_t)(t0 + ar) * K + ak;
  const u16* wptr = W + (size_t)bk * N + c0 + bc;

  for (int k0 = 0; k0 < K; k0 += 32) {
    uint4 a0 = make_uint4(0, 0, 0, 0), a1 = a0;
    if (arow_ok) {
      a0 = *(const uint4*)(aptr + k0);
      a1 = *(const uint4*)(aptr + k0 + 8);
    }
    uint4 w0 = *(const uint4*)(wptr + (size_t)k0 * N);
    uint4 w1v = *(const uint4*)(wptr + (size_t)k0 * N + 8);

    *(uint4*)&lA[ar * 40 + ak]     = a0;
    *(uint4*)&lA[ar * 40 + ak + 8] = a1;
    {
      u16 tmp[16];
      *(uint4*)tmp       = w0;
      *(uint4*)(tmp + 8) = w1v;
      const int kb = bk >> 3, ke = bk & 7;
      char* base = (char*)lB;
#pragma unroll
      for (int i = 0; i < 16; ++i) {
        int col = bc + i;
        int off = (kb * 2048 + col * 16 + ke * 2) ^ (((col >> 3) & 7) << 4);
        *(u16*)(base + off) = tmp[i];
      }
    }
    __syncthreads();

    bf16x8 af[4], bfv[4];
#pragma unroll
    for (int m = 0; m < 4; ++m)
      af[m] = as_frag(*(const uint4*)&lA[(wr + m * 16 + l15) * 40 + l4 * 8]);
#pragma unroll
    for (int j = 0; j < 4; ++j) {
      int col = wc + j * 16 + l15;
      int off = (l4 * 2048 + col * 16) ^ (((col >> 3) & 7) << 4);
      bfv[j] = as_frag(*(const uint4*)((char*)lB + off));
    }
#pragma unroll
    for (int m = 0; m < 4; ++m)
#pragma unroll
      for (int j = 0; j < 4; ++j)
        acc[m][j] = __builtin_amdgcn_mfma_f32_16x16x32_bf16(af[m], bfv[j], acc[m][j], 0, 0, 0);
    __syncthreads();
  }

#pragma unroll
  for (int m = 0; m < 4; ++m) {
#pragma unroll
    for (int r = 0; r < 4; ++r) {
      int row = t0 + wr + m * 16 + l4 * 4 + r;
      if (row >= M) continue;
#pragma unroll
      for (int j = 0; j < 4; ++j) {
        int col = c0 + wc + j * 16 + l15;
        size_t idx = (size_t)row * N + col;
        float y = acc[m][j][r];
        if constexpr (EPI == EPI_SILU_BF16) {
          float s = y / (1.f + __expf(-y));          // silu
          ((u16*)C)[idx] = f2b(s);
        } else {
          ((float*)C)[idx] = y + ADD[idx];
        }
      }
    }
  }
}

// ---------------------------------------------------------------------------
// pos score table: pos_s[n][m] = pos_w[n-m+1023] * (m<=n), bf16, 1024x1024.
// ---------------------------------------------------------------------------
__global__ __launch_bounds__(128) void pos_scores(
    const float* __restrict__ pos_w, u16* __restrict__ pos_s)
{
  const int n = blockIdx.x;
  const int m0 = threadIdx.x * 8;
  u16 o[8];
#pragma unroll
  for (int i = 0; i < 8; ++i) {
    int m = m0 + i;
    float v = (m <= n) ? pos_w[n - m + 1023] : 0.f;
    o[i] = f2b(v);
  }
  *(uint4*)(pos_s + (size_t)n * 1024 + m0) = *(uint4*)o;
}

// ---------------------------------------------------------------------------
// ts score panels: for (b, nt), 128 rows (n = n0+r) x W cols (m = 0..W-1),
// W = 128*(nt+1):  ts_s = ts_w[clip(floor(log1p|dt|*SCALE),0,128)] * (m<=n).
// ---------------------------------------------------------------------------
__global__ __launch_bounds__(256) void ts_scores(
    const int* __restrict__ tstamp, const float* __restrict__ ts_w,
    u16* __restrict__ ts_s)
{
  const int nt = 7 - (blockIdx.x >> 6);
  const int b  = blockIdx.x & 63;
  const int W  = 128 * (nt + 1);
  const int n0 = nt * 128;
  const int tid = threadIdx.x;

  __shared__ float tsw[132];
  __shared__ int   tsm[1024];
  if (tid < 129) tsw[tid] = ts_w[tid];
  for (int i = tid; i < W; i += 256) tsm[i] = tstamp[b * 1024 + i];
  __syncthreads();

  const int r = tid >> 1, h = tid & 1;
  const int n_abs = n0 + r;
  const int t_n = tstamp[b * 1024 + n_abs];
  u16* row = ts_s + ts_base_elems(b, nt) + (size_t)r * W + h * (W >> 1);
  const int c0 = h * (W >> 1);
  const int half = W >> 1;

  for (int c = 0; c < half; c += 8) {
    u16 o[8];
#pragma unroll
    for (int i = 0; i < 8; ++i) {
      int m = c0 + c + i;
      int d = t_n - tsm[m];
      if (d < 0) d = -d;
      float dt = (float)d;
      int bkt = (int)(log1pf(dt) * TS_SCALE_F);   // >=0 so trunc == floor
      bkt = bkt > 128 ? 128 : bkt;
      float v = (m <= n_abs) ? tsw[bkt] : 0.f;
      o[i] = f2b(v);
    }
    *(uint4*)(row + c) = *(uint4*)o;
  }
}

// ---------------------------------------------------------------------------
// Attention as dual GEMM: per (b, nt, ct) block compute
//   out_pos = pos_s[n0:n0+128, :] @ V,  out_ts = ts_s(b,nt) @ V
// with V gathered from proj cols [1024,1536), ragged rows zeroed.
// Output bf16, head-interleaved layout of concat([pos,ts],-1).reshape(.,1024).
// ---------------------------------------------------------------------------
__global__ __launch_bounds__(256, 1) void attn_gemm(
    const u16* __restrict__ proj,      // T x 1536 bf16
    const int* __restrict__ xoff,      // B+1 (int32)
    const u16* __restrict__ pos_s,     // 1024 x 1024 bf16
    const u16* __restrict__ ts_s,      // panels
    u16* __restrict__ attn_out,        // T x 1024 bf16 (scratch in d_out)
    int Ttot)
{
  const int flat = blockIdx.x;
  const int nt = 7 - (flat >> 8);          // heavy tiles dispatched first
  const int rem = flat & 255;
  const int b  = rem >> 2;
  const int ct = rem & 3;

  const int off = xoff[b];
  int len = xoff[b + 1] - off;
  if (len < 0) len = 0;
  if (len > 1024) len = 1024;
  if (off < 0 || off + len > Ttot) return;
  const int n0 = nt * 128;
  if (n0 >= len) return;
  const int c0 = ct * 128;
  const int W = 128 * (nt + 1);

  __shared__ u16 lP[128 * 40];
  __shared__ u16 lT[128 * 40];
  __shared__ u16 sV[4096];

  const int tid = threadIdx.x;
  const int wave = tid >> 6, lane = tid & 63;
  const int wr = (wave >> 1) * 64, wc = (wave & 1) * 64;
  const int l15 = lane & 15, l4 = lane >> 4;

  f32x4 z = {0.f, 0.f, 0.f, 0.f};
  f32x4 accP[4][4], accT[4][4];
#pragma unroll
  for (int m = 0; m < 4; ++m)
#pragma unroll
    for (int j = 0; j < 4; ++j) { accP[m][j] = z; accT[m][j] = z; }

  const int ar = tid >> 1, ak = (tid & 1) * 16;
  const u16* pRow = pos_s + (size_t)(n0 + ar) * 1024 + ak;
  const u16* tRow = ts_s + ts_base_elems(b, nt) + (size_t)ar * W + ak;
  const int vk = tid >> 3, vc = (tid & 7) * 16;

  const int mEnd = (n0 + 128 < len) ? (n0 + 128) : len;

  for (int m0 = 0; m0 < mEnd; m0 += 32) {
    // ---- stage V tile (32 x 128), transposed+swizzled, ragged-zeroed ----
    {
      int mm = m0 + vk;
      uint4 v0 = make_uint4(0, 0, 0, 0), v1 = v0;
      if (mm < len) {
        const u16* src = proj + (size_t)(off + mm) * 1536 + 1024 + c0 + vc;
        v0 = *(const uint4*)src;
        v1 = *(const uint4*)(src + 8);
      }
      u16 tmp[16];
      *(uint4*)tmp       = v0;
      *(uint4*)(tmp + 8) = v1;
      const int kb = vk >> 3, ke = vk & 7;
#pragma unroll
      for (int i = 0; i < 16; ++i) {
        int col = vc + i;
        int o2 = (kb * 2048 + col * 16 + ke * 2) ^ (((col >> 3) & 7) << 4);
        *(u16*)((char*)sV + o2) = tmp[i];
      }
    }
    // ---- stage score tiles (128 x 32) from global ----
    {
      uint4 p0 = *(const uint4*)(pRow + m0);
      uint4 p1 = *(const uint4*)(pRow + m0 + 8);
      uint4 t0v = *(const uint4*)(tRow + m0);
      uint4 t1v = *(const uint4*)(tRow + m0 + 8);
      int wb = ar * 40 + ak;
      *(uint4*)&lP[wb]     = p0;
      *(uint4*)&lP[wb + 8] = p1;
      *(uint4*)&lT[wb]     = t0v;
      *(uint4*)&lT[wb + 8] = t1v;
    }
    __syncthreads();

    bf16x8 ap[4], at[4], bv[4];
#pragma unroll
    for (int m = 0; m < 4; ++m) {
      ap[m] = as_frag(*(const uint4*)&lP[(wr + m * 16 + l15) * 40 + l4 * 8]);
      at[m] = as_frag(*(const uint4*)&lT[(wr + m * 16 + l15) * 40 + l4 * 8]);
    }
#pragma unroll
    for (int j = 0; j < 4; ++j) {
      int col = wc + j * 16 + l15;
      int o2 = (l4 * 2048 + col * 16) ^ (((col >> 3) & 7) << 4);
      bv[j] = as_frag(*(const uint4*)((char*)sV + o2));
    }
#pragma unroll
    for (int m = 0; m < 4; ++m)
#pragma unroll
      for (int j = 0; j < 4; ++j) {
        accP[m][j] = __builtin_amdgcn_mfma_f32_16x16x32_bf16(ap[m], bv[j], accP[m][j], 0, 0, 0);
        accT[m][j] = __builtin_amdgcn_mfma_f32_16x16x32_bf16(at[m], bv[j], accT[m][j], 0, 0, 0);
      }
    __syncthreads();
  }

  // ---- store bf16 with head-interleaved combined layout ----
#pragma unroll
  for (int m = 0; m < 4; ++m)
#pragma unroll
    for (int r = 0; r < 4; ++r) {
      int n = n0 + wr + m * 16 + l4 * 4 + r;
      if (n >= len) continue;
      size_t t = (size_t)(off + n);
#pragma unroll
      for (int j = 0; j < 4; ++j) {
        int hd = c0 + wc + j * 16 + l15;            // 0..511
        int colP = ((hd >> 6) << 7) + (hd & 63);    // h*128 + d
        attn_out[t * 1024 + colP]      = f2b(accP[m][j][r]);
        attn_out[t * 1024 + colP + 64] = f2b(accT[m][j][r]);
      }
    }
}

// ---------------------------------------------------------------------------
// Row-wise RMS norm prep: out_bf16[row] = rmsnorm(in[row]) (* mul[row] opt.)
// ---------------------------------------------------------------------------
template <int D, bool HASMUL, bool INBF>
__global__ __launch_bounds__(256) void rms_prep(
    const void* __restrict__ in_, const u16* __restrict__ mul, int mulStride,
    u16* __restrict__ out)
{
  const int row = blockIdx.x;
  const int tid = threadIdx.x;
  const float* rf = (const float*)in_ + (INBF ? 0 : (size_t)row * D);
  const u16*   rb = (const u16*)in_ + (INBF ? (size_t)row * D : 0);
  float ss = 0.f;
#pragma unroll
  for (int i = tid; i < D; i += 256) {
    float v = INBF ? b2f(rb[i]) : rf[i];
    ss += v * v;
  }
#pragma unroll
  for (int o = 32; o > 0; o >>= 1) ss += __shfl_down(ss, o, 64);
  __shared__ float sred[4];
  const int wave = tid >> 6, lane = tid & 63;
  if (lane == 0) sred[wave] = ss;
  __syncthreads();
  float inv = rsqrtf((sred[0] + sred[1] + sred[2] + sred[3]) / (float)D + 1e-6f);
#pragma unroll
  for (int i = tid; i < D; i += 256) {
    float v = (INBF ? b2f(rb[i]) : rf[i]) * inv;
    if constexpr (HASMUL) v *= b2f(mul[(size_t)row * mulStride + i]);
    out[(size_t)row * D + i] = f2b(v);
  }
}

__global__ void cvt_bf16(const float* __restrict__ in, u16* __restrict__ out, int n) {
  int i = blockIdx.x * 256 + threadIdx.x;
  if (i < n) out[i] = f2b(in[i]);
}

// ---------------------------------------------------------------------------
extern "C" void kernel_launch(void* const* d_in, const int* in_sizes, int n_in,
                              void* d_out, int out_size, void* d_ws, size_t ws_size,
                              hipStream_t stream)
{
  const float* x      = (const float*)d_in[0];
  const int*   xoff   = (const int*)d_in[1];    // int32 per harness contract
  const int*   tstamp = (const int*)d_in[2];    // int32 per harness contract
  // d_in[3] = invalid_attn_mask (tril) -- implied by causal masking, unused
  const float* uv     = (const float*)d_in[4];
  const float* pos_w  = (const float*)d_in[5];
  const float* ts_w   = (const float*)d_in[6];
  const float* w_ams  = (const float*)d_in[7];
  const float* w1     = (const float*)d_in[8];
  const float* w2     = (const float*)d_in[9];
  const int T = in_sizes[0] / 512;

  char* ws = (char*)d_ws;
  size_t o = 0;
  auto take = [&](size_t bytes) { size_t r = o; o += (bytes + 255) & ~(size_t)255; return r; };

  // --- static small buffers ---
  u16* uvb    = (u16*)(ws + take((size_t)512 * 1536 * 2));
  u16* wamsb  = (u16*)(ws + take((size_t)1024 * 512 * 2));
  u16* w1b    = (u16*)(ws + take((size_t)512 * 2048 * 2));
  u16* w2b    = (u16*)(ws + take((size_t)2048 * 512 * 2));
  u16* posS   = (u16*)(ws + take((size_t)1024 * 1024 * 2));   // 2 MB

  // --- S2 region: A1 -> tsS -> A2 -> mid(head). All lifetimes disjoint. ---
  size_t tsBytes = (size_t)64 * 589824 * 2;                   // 75.5 MB
  size_t s2Bytes = (size_t)T * 1024 * 2;                      // A2: T x 1024 bf16
  if (s2Bytes < tsBytes) s2Bytes = tsBytes;
  size_t o_s2 = take(s2Bytes);
  u16* A1   = (u16*)(ws + o_s2);            // rmsnorm(x) bf16  [phases A-B]
  u16* tsS  = (u16*)(ws + o_s2);            // ts panels        [phases C-D]
  u16* A2   = (u16*)(ws + o_s2);            // u*rmsnorm(attn)  [phases E-F]
  u16* mid  = (u16*)(ws + o_s2);            // T x 2048 bf16    [phases H-I]
                                            // spans S2 + proj head

  // --- proj region (adjacent to S2; mid overflows into its head) ---
  size_t o_proj = take((size_t)T * 1536 * 2);
  u16* proj = (u16*)(ws + o_proj);          // silu proj bf16 (u|v) [B-E]
  u16* A1p  = proj + (size_t)T * 1024;      // rmsnorm(h) in proj tail [G-H]
                                            // tail starts at byte T*2048;
                                            // mid ends at o_s2 + T*4096
                                            //  <= o_proj + T*2048 (since
                                            // s2Bytes >= T*2048)  -> no overlap

  u16*   attnS = (u16*)d_out;               // attn bf16 scratch (T*2048 B fits
                                            // exactly in T*512 f32)
  float* h     = (float*)d_out;             // h lives in d_out afterwards

  // If the workspace is too small, launch nothing: clean absmax failure
  // (diagnostic) instead of an OOB fault.
  if (ws_size < o) return;

  // weight conversions f32 -> bf16
  cvt_bf16<<<(512 * 1536 + 255) / 256, 256, 0, stream>>>(uv, uvb, 512 * 1536);
  cvt_bf16<<<(1024 * 512 + 255) / 256, 256, 0, stream>>>(w_ams, wamsb, 1024 * 512);
  cvt_bf16<<<(512 * 2048 + 255) / 256, 256, 0, stream>>>(w1, w1b, 512 * 2048);
  cvt_bf16<<<(2048 * 512 + 255) / 256, 256, 0, stream>>>(w2, w2b, 2048 * 512);

  // pos score table (independent)
  pos_scores<<<1024, 128, 0, stream>>>(pos_w, posS);

  // A = bf16(rmsnorm(x)) -> S2
  rms_prep<512, false, false><<<T, 256, 0, stream>>>(x, nullptr, 0, A1);

  // B: proj = silu(A1 @ uv)   (T x 1536)
  dim3 g1((T + 127) / 128, 12);
  gemm_bf16<EPI_SILU_BF16><<<g1, 256, 0, stream>>>(A1, uvb, proj, nullptr, T, 1536, 512);

  // C: ts panels -> S2 (overwrites A1; stream order guarantees B is done)
  ts_scores<<<512, 256, 0, stream>>>(tstamp, ts_w, tsS);

  // D: attention -> d_out as bf16 (head-interleaved pos/ts)
  attn_gemm<<<64 * 32, 256, 0, stream>>>(proj, xoff, posS, tsS, attnS, T);

  // E: A2 = bf16(u * rmsnorm(attn)) -> S2 (tsS dead)
  rms_prep<1024, true, true><<<T, 256, 0, stream>>>(attnS, proj, 1536, A2);

  // F: h = x + A2 @ w_ams   (T x 512) -> d_out (attn scratch dead)
  dim3 g3((T + 127) / 128, 4);
  gemm_bf16<EPI_ADD_F32><<<g3, 256, 0, stream>>>(A2, wamsb, h, x, T, 512, 1024);

  // G: A1' = bf16(rmsnorm(h)) -> proj tail (proj dead)
  rms_prep<512, false, false><<<T, 256, 0, stream>>>(h, nullptr, 0, A1p);

  // H: mid = silu(A1' @ w1)   (T x 2048) -> S2 + proj head (A2 dead)
  dim3 g4((T + 127) / 128, 16);
  gemm_bf16<EPI_SILU_BF16><<<g4, 256, 0, stream>>>(A1p, w1b, mid, nullptr, T, 2048, 512);

  // I: out = h + mid @ w2    (T x 512), in-place on d_out
  dim3 g5((T + 127) / 128, 4);
  gemm_bf16<EPI_ADD_F32><<<g5, 256, 0, stream>>>(mid, w2b, h, h, T, 512, 2048);
}

// Round 5
// 939.452 us; speedup vs baseline: 1.8279x; 1.0464x over previous
//
#include <hip/hip_runtime.h>
#include <cmath>

// ---------------------------------------------------------------------------
// SemanticFreeFuXiBlock on MI355X (gfx950), bf16 MFMA implementation.
// B=64, N=1024, D=512, H=8, LD=64, HIDDEN=2048, NB=128, T = in_sizes[0]/512.
// Round 5: GEMM overhaul:
//   - weights pre-transposed once (wprep) into the exact LDS image layout
//     [panel p][kstep s][kb 0..3][col 0..127][ke 0..7] (bf16) so B staging is
//     a straight global_load_lds width=16 (linear LDS, conflict-free reads,
//     no XOR swizzle needed anywhere in the GEMM).
//   - grid swapped: blockIdx.x = col-tile (fastest) -> adjacent blocks share
//     the A-tile -> A fetched ~once instead of once per col sweep.
// ---------------------------------------------------------------------------

using u16 = unsigned short;

typedef __bf16 bf16x8 __attribute__((ext_vector_type(8)));
typedef float  f32x4  __attribute__((ext_vector_type(4)));

#define TS_SCALE_F (float)(128.0 / 14.0)

__device__ __forceinline__ u16 f2b(float f) {            // RNE f32 -> bf16 bits
  unsigned u = __float_as_uint(f);
  unsigned r = 0x7FFFu + ((u >> 16) & 1u);
  return (u16)((u + r) >> 16);
}
__device__ __forceinline__ float b2f(u16 v) {
  return __uint_as_float(((unsigned)v) << 16);
}
__device__ __forceinline__ bf16x8 as_frag(uint4 r) {
  union { uint4 u; bf16x8 v; } c; c.u = r; return c.v;
}

// async global->LDS, 16 bytes per lane (lds dest: wave base + lane*16)
__device__ __forceinline__ void gload_lds16(const u16* g, u16* l) {
  __builtin_amdgcn_global_load_lds(
      (const __attribute__((address_space(1))) unsigned int*)g,
      (__attribute__((address_space(3))) unsigned int*)l, 16, 0, 0);
}

// ts_s panel base (elements): per batch 36*16384 elems; per nt prefix
// 16384 * nt*(nt+1)/2; panel (b,nt) is 128 rows x W cols, W = 128*(nt+1).
__device__ __forceinline__ size_t ts_base_elems(int b, int nt) {
  return (size_t)b * 589824 + (size_t)(nt * (nt + 1) / 2) * 16384;
}

// ---------------------------------------------------------------------------
// Weight pre-transpose: W (KxN f32 row-major) -> Wp bf16 panels.
// Wp elem offset = ((p*(K/32)+s)*4 + kb)*1024 + c*8 + ke
//   holds W[s*32 + kb*8 + ke][p*128 + c].
// grid = (N/128, K/32), 256 threads; each thread writes 16 consecutive u16.
// ---------------------------------------------------------------------------
__global__ __launch_bounds__(256) void wprep(
    const float* __restrict__ W, u16* __restrict__ Wp, int K, int N)
{
  const int p = blockIdx.x, s = blockIdx.y;
  const int t = threadIdx.x;
  size_t base = ((size_t)p * (K >> 5) + s) * 4096;
  const int e0 = t * 16;
  u16 o[16];
#pragma unroll
  for (int i = 0; i < 16; ++i) {
    int e = e0 + i;
    int kb = e >> 10, r = e & 1023, c = r >> 3, ke = r & 7;
    o[i] = f2b(W[(size_t)(s * 32 + kb * 8 + ke) * N + p * 128 + c]);
  }
  *(uint4*)(Wp + base + e0)     = *(uint4*)o;
  *(uint4*)(Wp + base + e0 + 8) = *(uint4*)(o + 8);
}

// ---------------------------------------------------------------------------
// Generic bf16 GEMM: C(MxN) = epilogue(A(MxK) @ W(KxN)), W pre-transposed.
// Tile 128x128x32, 256 threads = 4 waves (2x2 of 64x64), mfma_f32_16x16x32_bf16.
// lA: [128][40] u16 (pad 40 -> 2-way bank alias = free), reg-staged.
// lB: [kb][col][ke] linear 4096 u16, staged via global_load_lds (2 per wave).
// grid: x = col tile (fastest, shares A-tile), y = row tile.
// ---------------------------------------------------------------------------
#define EPI_SILU_BF16 0
#define EPI_ADD_F32   1

template <int EPI>
__global__ __launch_bounds__(256, 2) void gemm_bf16(
    const u16* __restrict__ A, const u16* __restrict__ Wp,
    void* __restrict__ C, const float* __restrict__ ADD,
    int M, int N, int K)
{
  __shared__ u16 lA[128 * 40];
  __shared__ u16 lB[4096];

  const int tid  = threadIdx.x;
  const int c0b  = blockIdx.x;
  const int t0   = blockIdx.y * 128;
  const int c0   = c0b * 128;
  const int wave = tid >> 6, lane = tid & 63;
  const int wr   = (wave >> 1) * 64, wc = (wave & 1) * 64;
  const int l15  = lane & 15, l4 = lane >> 4;

  f32x4 z = {0.f, 0.f, 0.f, 0.f};
  f32x4 acc[4][4];
#pragma unroll
  for (int m = 0; m < 4; ++m)
#pragma unroll
    for (int j = 0; j < 4; ++j) acc[m][j] = z;

  const int ar = tid >> 1, ak = (tid & 1) * 16;      // A stage: 16 bf16 along K
  const bool arow_ok = (t0 + ar) < M;
  const u16* aptr = A + (size_t)(t0 + ar) * K + ak;
  const int ksteps = K >> 5;
  const u16* wpanel = Wp + (size_t)c0b * ksteps * 4096;
  const u16* wsrc = wpanel + wave * 1024 + lane * 8;  // per-lane 16B chunk
  u16* ldsb = &lB[wave * 1024];

  for (int s = 0; s < ksteps; ++s) {
    uint4 a0 = make_uint4(0, 0, 0, 0), a1 = a0;
    if (arow_ok) {
      a0 = *(const uint4*)(aptr);
      a1 = *(const uint4*)(aptr + 8);
    }
    aptr += 32;
    // B: async DMA, 2 x 1KB per wave
    gload_lds16(wsrc, ldsb);
    gload_lds16(wsrc + 512, ldsb + 512);
    wsrc += 4096;
    // A: reg-staged vector writes into padded rows
    *(uint4*)&lA[ar * 40 + ak]     = a0;
    *(uint4*)&lA[ar * 40 + ak + 8] = a1;
    __syncthreads();

    bf16x8 af[4], bfv[4];
#pragma unroll
    for (int m = 0; m < 4; ++m)
      af[m] = as_frag(*(const uint4*)&lA[(wr + m * 16 + l15) * 40 + l4 * 8]);
#pragma unroll
    for (int j = 0; j < 4; ++j)
      bfv[j] = as_frag(*(const uint4*)&lB[(l4 << 10) + (wc + j * 16 + l15) * 8]);
#pragma unroll
    for (int m = 0; m < 4; ++m)
#pragma unroll
      for (int j = 0; j < 4; ++j)
        acc[m][j] = __builtin_amdgcn_mfma_f32_16x16x32_bf16(af[m], bfv[j], acc[m][j], 0, 0, 0);
    __syncthreads();
  }

#pragma unroll
  for (int m = 0; m < 4; ++m) {
#pragma unroll
    for (int r = 0; r < 4; ++r) {
      int row = t0 + wr + m * 16 + l4 * 4 + r;
      if (row >= M) continue;
#pragma unroll
      for (int j = 0; j < 4; ++j) {
        int col = c0 + wc + j * 16 + l15;
        size_t idx = (size_t)row * N + col;
        float y = acc[m][j][r];
        if constexpr (EPI == EPI_SILU_BF16) {
          float s = y / (1.f + __expf(-y));          // silu
          ((u16*)C)[idx] = f2b(s);
        } else {
          ((float*)C)[idx] = y + ADD[idx];
        }
      }
    }
  }
}

// ---------------------------------------------------------------------------
// pos score table: pos_s[n][m] = pos_w[n-m+1023] * (m<=n), bf16, 1024x1024.
// ---------------------------------------------------------------------------
__global__ __launch_bounds__(128) void pos_scores(
    const float* __restrict__ pos_w, u16* __restrict__ pos_s)
{
  const int n = blockIdx.x;
  const int m0 = threadIdx.x * 8;
  u16 o[8];
#pragma unroll
  for (int i = 0; i < 8; ++i) {
    int m = m0 + i;
    float v = (m <= n) ? pos_w[n - m + 1023] : 0.f;
    o[i] = f2b(v);
  }
  *(uint4*)(pos_s + (size_t)n * 1024 + m0) = *(uint4*)o;
}

// ---------------------------------------------------------------------------
// ts score panels: for (b, nt), 128 rows (n = n0+r) x W cols (m = 0..W-1),
// W = 128*(nt+1):  ts_s = ts_w[clip(floor(log1p|dt|*SCALE),0,128)] * (m<=n).
// ---------------------------------------------------------------------------
__global__ __launch_bounds__(256) void ts_scores(
    const int* __restrict__ tstamp, const float* __restrict__ ts_w,
    u16* __restrict__ ts_s)
{
  const int nt = 7 - (blockIdx.x >> 6);
  const int b  = blockIdx.x & 63;
  const int W  = 128 * (nt + 1);
  const int n0 = nt * 128;
  const int tid = threadIdx.x;

  __shared__ float tsw[132];
  __shared__ int   tsm[1024];
  if (tid < 129) tsw[tid] = ts_w[tid];
  for (int i = tid; i < W; i += 256) tsm[i] = tstamp[b * 1024 + i];
  __syncthreads();

  const int r = tid >> 1, h = tid & 1;
  const int n_abs = n0 + r;
  const int t_n = tstamp[b * 1024 + n_abs];
  u16* row = ts_s + ts_base_elems(b, nt) + (size_t)r * W + h * (W >> 1);
  const int c0 = h * (W >> 1);
  const int half = W >> 1;

  for (int c = 0; c < half; c += 8) {
    u16 o[8];
#pragma unroll
    for (int i = 0; i < 8; ++i) {
      int m = c0 + c + i;
      int d = t_n - tsm[m];
      if (d < 0) d = -d;
      float dt = (float)d;
      int bkt = (int)(log1pf(dt) * TS_SCALE_F);   // >=0 so trunc == floor
      bkt = bkt > 128 ? 128 : bkt;
      float v = (m <= n_abs) ? tsw[bkt] : 0.f;
      o[i] = f2b(v);
    }
    *(uint4*)(row + c) = *(uint4*)o;
  }
}

// ---------------------------------------------------------------------------
// Attention as dual GEMM: per (b, nt, ct) block compute
//   out_pos = pos_s[n0:n0+128, :] @ V,  out_ts = ts_s(b,nt) @ V
// with V gathered from proj cols [1024,1536), ragged rows zeroed.
// Output bf16, head-interleaved layout of concat([pos,ts],-1).reshape(.,1024).
// ---------------------------------------------------------------------------
__global__ __launch_bounds__(256, 1) void attn_gemm(
    const u16* __restrict__ proj,      // T x 1536 bf16
    const int* __restrict__ xoff,      // B+1 (int32)
    const u16* __restrict__ pos_s,     // 1024 x 1024 bf16
    const u16* __restrict__ ts_s,      // panels
    u16* __restrict__ attn_out,        // T x 1024 bf16 (scratch in d_out)
    int Ttot)
{
  const int flat = blockIdx.x;
  const int nt = 7 - (flat >> 8);          // heavy tiles dispatched first
  const int rem = flat & 255;
  const int b  = rem >> 2;
  const int ct = rem & 3;

  const int off = xoff[b];
  int len = xoff[b + 1] - off;
  if (len < 0) len = 0;
  if (len > 1024) len = 1024;
  if (off < 0 || off + len > Ttot) return;
  const int n0 = nt * 128;
  if (n0 >= len) return;
  const int c0 = ct * 128;
  const int W = 128 * (nt + 1);

  __shared__ u16 lP[128 * 40];
  __shared__ u16 lT[128 * 40];
  __shared__ u16 sV[4096];

  const int tid = threadIdx.x;
  const int wave = tid >> 6, lane = tid & 63;
  const int wr = (wave >> 1) * 64, wc = (wave & 1) * 64;
  const int l15 = lane & 15, l4 = lane >> 4;

  f32x4 z = {0.f, 0.f, 0.f, 0.f};
  f32x4 accP[4][4], accT[4][4];
#pragma unroll
  for (int m = 0; m < 4; ++m)
#pragma unroll
    for (int j = 0; j < 4; ++j) { accP[m][j] = z; accT[m][j] = z; }

  const int ar = tid >> 1, ak = (tid & 1) * 16;
  const u16* pRow = pos_s + (size_t)(n0 + ar) * 1024 + ak;
  const u16* tRow = ts_s + ts_base_elems(b, nt) + (size_t)ar * W + ak;
  const int vk = tid >> 3, vc = (tid & 7) * 16;

  const int mEnd = (n0 + 128 < len) ? (n0 + 128) : len;

  for (int m0 = 0; m0 < mEnd; m0 += 32) {
    // ---- stage V tile (32 x 128), transposed+swizzled, ragged-zeroed ----
    {
      int mm = m0 + vk;
      uint4 v0 = make_uint4(0, 0, 0, 0), v1 = v0;
      if (mm < len) {
        const u16* src = proj + (size_t)(off + mm) * 1536 + 1024 + c0 + vc;
        v0 = *(const uint4*)src;
        v1 = *(const uint4*)(src + 8);
      }
      u16 tmp[16];
      *(uint4*)tmp       = v0;
      *(uint4*)(tmp + 8) = v1;
      const int kb = vk >> 3, ke = vk & 7;
#pragma unroll
      for (int i = 0; i < 16; ++i) {
        int col = vc + i;
        int o2 = (kb * 2048 + col * 16 + ke * 2) ^ (((col >> 3) & 7) << 4);
        *(u16*)((char*)sV + o2) = tmp[i];
      }
    }
    // ---- stage score tiles (128 x 32) from global ----
    {
      uint4 p0 = *(const uint4*)(pRow + m0);
      uint4 p1 = *(const uint4*)(pRow + m0 + 8);
      uint4 t0v = *(const uint4*)(tRow + m0);
      uint4 t1v = *(const uint4*)(tRow + m0 + 8);
      int wb = ar * 40 + ak;
      *(uint4*)&lP[wb]     = p0;
      *(uint4*)&lP[wb + 8] = p1;
      *(uint4*)&lT[wb]     = t0v;
      *(uint4*)&lT[wb + 8] = t1v;
    }
    __syncthreads();

    bf16x8 ap[4], at[4], bv[4];
#pragma unroll
    for (int m = 0; m < 4; ++m) {
      ap[m] = as_frag(*(const uint4*)&lP[(wr + m * 16 + l15) * 40 + l4 * 8]);
      at[m] = as_frag(*(const uint4*)&lT[(wr + m * 16 + l15) * 40 + l4 * 8]);
    }
#pragma unroll
    for (int j = 0; j < 4; ++j) {
      int col = wc + j * 16 + l15;
      int o2 = (l4 * 2048 + col * 16) ^ (((col >> 3) & 7) << 4);
      bv[j] = as_frag(*(const uint4*)((char*)sV + o2));
    }
#pragma unroll
    for (int m = 0; m < 4; ++m)
#pragma unroll
      for (int j = 0; j < 4; ++j) {
        accP[m][j] = __builtin_amdgcn_mfma_f32_16x16x32_bf16(ap[m], bv[j], accP[m][j], 0, 0, 0);
        accT[m][j] = __builtin_amdgcn_mfma_f32_16x16x32_bf16(at[m], bv[j], accT[m][j], 0, 0, 0);
      }
    __syncthreads();
  }

  // ---- store bf16 with head-interleaved combined layout ----
#pragma unroll
  for (int m = 0; m < 4; ++m)
#pragma unroll
    for (int r = 0; r < 4; ++r) {
      int n = n0 + wr + m * 16 + l4 * 4 + r;
      if (n >= len) continue;
      size_t t = (size_t)(off + n);
#pragma unroll
      for (int j = 0; j < 4; ++j) {
        int hd = c0 + wc + j * 16 + l15;            // 0..511
        int colP = ((hd >> 6) << 7) + (hd & 63);    // h*128 + d
        attn_out[t * 1024 + colP]      = f2b(accP[m][j][r]);
        attn_out[t * 1024 + colP + 64] = f2b(accT[m][j][r]);
      }
    }
}

// ---------------------------------------------------------------------------
// Row-wise RMS norm prep: out_bf16[row] = rmsnorm(in[row]) (* mul[row] opt.)
// ---------------------------------------------------------------------------
template <int D, bool HASMUL, bool INBF>
__global__ __launch_bounds__(256) void rms_prep(
    const void* __restrict__ in_, const u16* __restrict__ mul, int mulStride,
    u16* __restrict__ out)
{
  const int row = blockIdx.x;
  const int tid = threadIdx.x;
  const float* rf = (const float*)in_ + (INBF ? 0 : (size_t)row * D);
  const u16*   rb = (const u16*)in_ + (INBF ? (size_t)row * D : 0);
  float ss = 0.f;
#pragma unroll
  for (int i = tid; i < D; i += 256) {
    float v = INBF ? b2f(rb[i]) : rf[i];
    ss += v * v;
  }
#pragma unroll
  for (int o = 32; o > 0; o >>= 1) ss += __shfl_down(ss, o, 64);
  __shared__ float sred[4];
  const int wave = tid >> 6, lane = tid & 63;
  if (lane == 0) sred[wave] = ss;
  __syncthreads();
  float inv = rsqrtf((sred[0] + sred[1] + sred[2] + sred[3]) / (float)D + 1e-6f);
#pragma unroll
  for (int i = tid; i < D; i += 256) {
    float v = (INBF ? b2f(rb[i]) : rf[i]) * inv;
    if constexpr (HASMUL) v *= b2f(mul[(size_t)row * mulStride + i]);
    out[(size_t)row * D + i] = f2b(v);
  }
}

// ---------------------------------------------------------------------------
extern "C" void kernel_launch(void* const* d_in, const int* in_sizes, int n_in,
                              void* d_out, int out_size, void* d_ws, size_t ws_size,
                              hipStream_t stream)
{
  const float* x      = (const float*)d_in[0];
  const int*   xoff   = (const int*)d_in[1];    // int32 per harness contract
  const int*   tstamp = (const int*)d_in[2];    // int32 per harness contract
  // d_in[3] = invalid_attn_mask (tril) -- implied by causal masking, unused
  const float* uv     = (const float*)d_in[4];
  const float* pos_w  = (const float*)d_in[5];
  const float* ts_w   = (const float*)d_in[6];
  const float* w_ams  = (const float*)d_in[7];
  const float* w1     = (const float*)d_in[8];
  const float* w2     = (const float*)d_in[9];
  const int T = in_sizes[0] / 512;

  char* ws = (char*)d_ws;
  size_t o = 0;
  auto take = [&](size_t bytes) { size_t r = o; o += (bytes + 255) & ~(size_t)255; return r; };

  // --- static small buffers (pre-transposed weight panels) ---
  u16* uvb    = (u16*)(ws + take((size_t)512 * 1536 * 2));
  u16* wamsb  = (u16*)(ws + take((size_t)1024 * 512 * 2));
  u16* w1b    = (u16*)(ws + take((size_t)512 * 2048 * 2));
  u16* w2b    = (u16*)(ws + take((size_t)2048 * 512 * 2));
  u16* posS   = (u16*)(ws + take((size_t)1024 * 1024 * 2));   // 2 MB

  // --- S2 region: A1 -> tsS -> A2 -> mid(head). All lifetimes disjoint. ---
  size_t tsBytes = (size_t)64 * 589824 * 2;                   // 75.5 MB
  size_t s2Bytes = (size_t)T * 1024 * 2;                      // A2: T x 1024 bf16
  if (s2Bytes < tsBytes) s2Bytes = tsBytes;
  size_t o_s2 = take(s2Bytes);
  u16* A1   = (u16*)(ws + o_s2);            // rmsnorm(x) bf16  [phases A-B]
  u16* tsS  = (u16*)(ws + o_s2);            // ts panels        [phases C-D]
  u16* A2   = (u16*)(ws + o_s2);            // u*rmsnorm(attn)  [phases E-F]
  u16* mid  = (u16*)(ws + o_s2);            // T x 2048 bf16    [phases H-I]

  // --- proj region (adjacent to S2; mid overflows into its head) ---
  size_t o_proj = take((size_t)T * 1536 * 2);
  u16* proj = (u16*)(ws + o_proj);          // silu proj bf16 (u|v) [B-E]
  u16* A1p  = proj + (size_t)T * 1024;      // rmsnorm(h) in proj tail [G-H]

  u16*   attnS = (u16*)d_out;               // attn bf16 scratch (T*2048 B fits
                                            // exactly in T*512 f32)
  float* h     = (float*)d_out;             // h lives in d_out afterwards

  // If the workspace is too small, launch nothing: clean absmax failure
  // (diagnostic) instead of an OOB fault.
  if (ws_size < o) return;

  // weight pre-transpose f32 -> bf16 LDS-image panels
  wprep<<<dim3(12, 16), 256, 0, stream>>>(uv,    uvb,   512,  1536);
  wprep<<<dim3(4, 32),  256, 0, stream>>>(w_ams, wamsb, 1024, 512);
  wprep<<<dim3(16, 16), 256, 0, stream>>>(w1,    w1b,   512,  2048);
  wprep<<<dim3(4, 64),  256, 0, stream>>>(w2,    w2b,   2048, 512);

  // pos score table (independent)
  pos_scores<<<1024, 128, 0, stream>>>(pos_w, posS);

  // A = bf16(rmsnorm(x)) -> S2
  rms_prep<512, false, false><<<T, 256, 0, stream>>>(x, nullptr, 0, A1);

  // B: proj = silu(A1 @ uv)   (T x 1536)
  dim3 g1(12, (T + 127) / 128);
  gemm_bf16<EPI_SILU_BF16><<<g1, 256, 0, stream>>>(A1, uvb, proj, nullptr, T, 1536, 512);

  // C: ts panels -> S2 (overwrites A1; stream order guarantees B is done)
  ts_scores<<<512, 256, 0, stream>>>(tstamp, ts_w, tsS);

  // D: attention -> d_out as bf16 (head-interleaved pos/ts)
  attn_gemm<<<64 * 32, 256, 0, stream>>>(proj, xoff, posS, tsS, attnS, T);

  // E: A2 = bf16(u * rmsnorm(attn)) -> S2 (tsS dead)
  rms_prep<1024, true, true><<<T, 256, 0, stream>>>(attnS, proj, 1536, A2);

  // F: h = x + A2 @ w_ams   (T x 512) -> d_out (attn scratch dead)
  dim3 g3(4, (T + 127) / 128);
  gemm_bf16<EPI_ADD_F32><<<g3, 256, 0, stream>>>(A2, wamsb, h, x, T, 512, 1024);

  // G: A1' = bf16(rmsnorm(h)) -> proj tail (proj dead)
  rms_prep<512, false, false><<<T, 256, 0, stream>>>(h, nullptr, 0, A1p);

  // H: mid = silu(A1' @ w1)   (T x 2048) -> S2 + proj head (A2 dead)
  dim3 g4(16, (T + 127) / 128);
  gemm_bf16<EPI_SILU_BF16><<<g4, 256, 0, stream>>>(A1p, w1b, mid, nullptr, T, 2048, 512);

  // I: out = h + mid @ w2    (T x 512), in-place on d_out
  dim3 g5(4, (T + 127) / 128);
  gemm_bf16<EPI_ADD_F32><<<g5, 256, 0, stream>>>(mid, w2b, h, h, T, 512, 2048);
}

// Round 6
// 930.444 us; speedup vs baseline: 1.8456x; 1.0097x over previous
//
#include <hip/hip_runtime.h>
#include <cmath>

// ---------------------------------------------------------------------------
// SemanticFreeFuXiBlock on MI355X (gfx950), bf16 MFMA implementation.
// B=64, N=1024, D=512, H=8, LD=64, HIDDEN=2048, NB=128, T = in_sizes[0]/512.
// Round 6:
//  - rms_prep kernels removed: per-row inv scales (row_ss) applied during
//    GEMM A-staging (AMODE): B: x*invX ; F: attn*invA*u ; H: h*invH.
//  - ts panels stored as u8 bucket indices (masked=129), LUT at attn staging.
//  - attn output moved to ws (F reads it while writing h to d_out -> no race).
//  - GEMM: single-barrier 2-phase pipeline, dbuf lA/lB, early async issue.
// ---------------------------------------------------------------------------

using u16 = unsigned short;
using u8  = unsigned char;

typedef __bf16 bf16x8 __attribute__((ext_vector_type(8)));
typedef float  f32x4  __attribute__((ext_vector_type(4)));

#define TS_SCALE_F (float)(128.0 / 14.0)

__device__ __forceinline__ u16 f2b(float f) {            // RNE f32 -> bf16 bits
  unsigned u = __float_as_uint(f);
  unsigned r = 0x7FFFu + ((u >> 16) & 1u);
  return (u16)((u + r) >> 16);
}
__device__ __forceinline__ float b2f(u16 v) {
  return __uint_as_float(((unsigned)v) << 16);
}
__device__ __forceinline__ bf16x8 as_frag(uint4 r) {
  union { uint4 u; bf16x8 v; } c; c.u = r; return c.v;
}

// async global->LDS, 16 bytes per lane (lds dest: wave base + lane*16)
__device__ __forceinline__ void gload_lds16(const u16* g, u16* l) {
  __builtin_amdgcn_global_load_lds(
      (const __attribute__((address_space(1))) unsigned int*)g,
      (__attribute__((address_space(3))) unsigned int*)l, 16, 0, 0);
}

// ts u8 panel base (bytes): per batch 589824; per nt prefix nt*(nt+1)/2*16384.
__device__ __forceinline__ size_t ts_base_u8(int b, int nt) {
  return (size_t)b * 589824 + (size_t)(nt * (nt + 1) / 2) * 16384;
}

// ---------------------------------------------------------------------------
// Weight pre-transpose: W (KxN f32 row-major) -> Wp bf16 panels.
// Wp elem offset = ((p*(K/32)+s)*4 + kb)*1024 + c*8 + ke
//   holds W[s*32 + kb*8 + ke][p*128 + c].
// ---------------------------------------------------------------------------
__global__ __launch_bounds__(256) void wprep(
    const float* __restrict__ W, u16* __restrict__ Wp, int K, int N)
{
  const int p = blockIdx.x, s = blockIdx.y;
  const int t = threadIdx.x;
  size_t base = ((size_t)p * (K >> 5) + s) * 4096;
  const int e0 = t * 16;
  u16 o[16];
#pragma unroll
  for (int i = 0; i < 16; ++i) {
    int e = e0 + i;
    int kb = e >> 10, r = e & 1023, c = r >> 3, ke = r & 7;
    o[i] = f2b(W[(size_t)(s * 32 + kb * 8 + ke) * N + p * 128 + c]);
  }
  *(uint4*)(Wp + base + e0)     = *(uint4*)o;
  *(uint4*)(Wp + base + e0 + 8) = *(uint4*)(o + 8);
}

// ---------------------------------------------------------------------------
// Generic bf16 GEMM, 2-phase pipelined: C = epi(Asrc @ W), W pre-transposed.
// Tile 128x128x32, 256 thr = 4 waves; dbuf lA (pad-40) + lB (linear image).
// AMODE: 0 = bf16 A; 1 = f32 A * inv[row]; 2 = bf16 A * inv[row] * bf16 U.
// ---------------------------------------------------------------------------
#define EPI_SILU_BF16 0
#define EPI_ADD_F32   1
#define AM_BF16   0
#define AM_F32S   1
#define AM_BF16SM 2

template <int EPI, int AMODE>
__global__ __launch_bounds__(256, 2) void gemm_bf16(
    const u16* __restrict__ A, const float* __restrict__ Af,
    const float* __restrict__ inv, const u16* __restrict__ U, int ustride,
    const u16* __restrict__ Wp, void* __restrict__ C,
    const float* __restrict__ ADD, int M, int N, int K)
{
  __shared__ u16 lA[2][128 * 40];
  __shared__ u16 lB[2][4096];

  const int tid  = threadIdx.x;
  const int c0b  = blockIdx.x;
  const int t0   = blockIdx.y * 128;
  const int c0   = c0b * 128;
  const int wave = tid >> 6, lane = tid & 63;
  const int wr   = (wave >> 1) * 64, wc = (wave & 1) * 64;
  const int l15  = lane & 15, l4 = lane >> 4;

  f32x4 z = {0.f, 0.f, 0.f, 0.f};
  f32x4 acc[4][4];
#pragma unroll
  for (int m = 0; m < 4; ++m)
#pragma unroll
    for (int j = 0; j < 4; ++j) acc[m][j] = z;

  const int ar = tid >> 1, ak = (tid & 1) * 16;      // A stage: 16 elems along K
  const int row = t0 + ar;
  const bool arow_ok = row < M;
  float rinv = 0.f;
  if (AMODE != AM_BF16 && arow_ok) rinv = inv[row];
  const u16*   ab = (AMODE != AM_F32S) ? A + (size_t)row * K + ak : nullptr;
  const float* af = (AMODE == AM_F32S) ? Af + (size_t)row * K + ak : nullptr;
  const u16*   um = (AMODE == AM_BF16SM) ? U + (size_t)row * ustride + ak : nullptr;

  uint4 pr[4];
  const uint4 z4 = make_uint4(0, 0, 0, 0);

  auto loadA = [&](int k0) {
    if (!arow_ok) { pr[0] = z4; pr[1] = z4; pr[2] = z4; pr[3] = z4; return; }
    if constexpr (AMODE == AM_BF16) {
      pr[0] = *(const uint4*)(ab + k0);
      pr[1] = *(const uint4*)(ab + k0 + 8);
    } else if constexpr (AMODE == AM_F32S) {
      pr[0] = *(const uint4*)(af + k0);
      pr[1] = *(const uint4*)(af + k0 + 4);
      pr[2] = *(const uint4*)(af + k0 + 8);
      pr[3] = *(const uint4*)(af + k0 + 12);
    } else {
      pr[0] = *(const uint4*)(ab + k0);
      pr[1] = *(const uint4*)(ab + k0 + 8);
      pr[2] = *(const uint4*)(um + k0);
      pr[3] = *(const uint4*)(um + k0 + 8);
    }
  };
  auto writeA = [&](u16* dst) {
    u16 tmp[16];
    if constexpr (AMODE == AM_BF16) {
      *(uint4*)tmp       = pr[0];
      *(uint4*)(tmp + 8) = pr[1];
    } else if constexpr (AMODE == AM_F32S) {
      const float* f = (const float*)pr;
#pragma unroll
      for (int i = 0; i < 16; ++i) tmp[i] = f2b(f[i] * rinv);
    } else {
      const u16* a = (const u16*)pr;
      const u16* u = (const u16*)(pr + 2);
#pragma unroll
      for (int i = 0; i < 16; ++i) tmp[i] = f2b(b2f(a[i]) * rinv * b2f(u[i]));
    }
    *(uint4*)(dst + ar * 40 + ak)     = *(uint4*)tmp;
    *(uint4*)(dst + ar * 40 + ak + 8) = *(uint4*)(tmp + 8);
  };

  const int ksteps = K >> 5;
  const u16* wsrc = Wp + (size_t)c0b * ksteps * 4096 + wave * 1024 + lane * 8;

  // prologue: stage step 0
  loadA(0);
  gload_lds16(wsrc,       &lB[0][wave * 1024]);
  gload_lds16(wsrc + 512, &lB[0][wave * 1024 + 512]);
  wsrc += 4096;
  writeA(&lA[0][0]);
  __syncthreads();

  int buf = 0;
  for (int s = 0; s < ksteps; ++s) {
    if (s + 1 < ksteps) {                 // issue next-step loads EARLY
      gload_lds16(wsrc,       &lB[buf ^ 1][wave * 1024]);
      gload_lds16(wsrc + 512, &lB[buf ^ 1][wave * 1024 + 512]);
      wsrc += 4096;
      loadA((s + 1) * 32);
    }
    const u16* lAc = &lA[buf][0];
    const u16* lBc = &lB[buf][0];
    bf16x8 afr[4], bfv[4];
#pragma unroll
    for (int m = 0; m < 4; ++m)
      afr[m] = as_frag(*(const uint4*)&lAc[(wr + m * 16 + l15) * 40 + l4 * 8]);
#pragma unroll
    for (int j = 0; j < 4; ++j)
      bfv[j] = as_frag(*(const uint4*)&lBc[(l4 << 10) + (wc + j * 16 + l15) * 8]);
#pragma unroll
    for (int m = 0; m < 4; ++m)
#pragma unroll
      for (int j = 0; j < 4; ++j)
        acc[m][j] = __builtin_amdgcn_mfma_f32_16x16x32_bf16(afr[m], bfv[j], acc[m][j], 0, 0, 0);
    if (s + 1 < ksteps) writeA(&lA[buf ^ 1][0]);
    __syncthreads();
    buf ^= 1;
  }

#pragma unroll
  for (int m = 0; m < 4; ++m) {
#pragma unroll
    for (int r = 0; r < 4; ++r) {
      int orow = t0 + wr + m * 16 + l4 * 4 + r;
      if (orow >= M) continue;
#pragma unroll
      for (int j = 0; j < 4; ++j) {
        int col = c0 + wc + j * 16 + l15;
        size_t idx = (size_t)orow * N + col;
        float y = acc[m][j][r];
        if constexpr (EPI == EPI_SILU_BF16) {
          float s = y / (1.f + __expf(-y));          // silu
          ((u16*)C)[idx] = f2b(s);
        } else {
          ((float*)C)[idx] = y + ADD[idx];
        }
      }
    }
  }
}

// ---------------------------------------------------------------------------
// pos score table: pos_s[n][m] = pos_w[n-m+1023] * (m<=n), bf16, 1024x1024.
// ---------------------------------------------------------------------------
__global__ __launch_bounds__(128) void pos_scores(
    const float* __restrict__ pos_w, u16* __restrict__ pos_s)
{
  const int n = blockIdx.x;
  const int m0 = threadIdx.x * 8;
  u16 o[8];
#pragma unroll
  for (int i = 0; i < 8; ++i) {
    int m = m0 + i;
    float v = (m <= n) ? pos_w[n - m + 1023] : 0.f;
    o[i] = f2b(v);
  }
  *(uint4*)(pos_s + (size_t)n * 1024 + m0) = *(uint4*)o;
}

// ---------------------------------------------------------------------------
// ts bucket panels (u8): for (b, nt), 128 rows x W cols, W = 128*(nt+1):
//   bucket = clip(floor(log1p|dt|*SCALE),0,128); masked (m>n) -> 129.
// ---------------------------------------------------------------------------
__global__ __launch_bounds__(256) void ts_buckets(
    const int* __restrict__ tstamp, u8* __restrict__ ts_s)
{
  const int nt = 7 - (blockIdx.x >> 6);
  const int b  = blockIdx.x & 63;
  const int W  = 128 * (nt + 1);
  const int n0 = nt * 128;
  const int tid = threadIdx.x;

  __shared__ int tsm[1024];
  for (int i = tid; i < W; i += 256) tsm[i] = tstamp[b * 1024 + i];
  __syncthreads();

  const int r = tid >> 1, h = tid & 1;
  const int n_abs = n0 + r;
  const int t_n = tstamp[b * 1024 + n_abs];
  const int half = W >> 1;
  const int c0 = h * half;
  u8* row = ts_s + ts_base_u8(b, nt) + (size_t)r * W + c0;

  for (int c = 0; c < half; c += 16) {
    u8 o[16];
#pragma unroll
    for (int i = 0; i < 16; ++i) {
      int m = c0 + c + i;
      int d = t_n - tsm[m];
      if (d < 0) d = -d;
      int bkt = (int)(log1pf((float)d) * TS_SCALE_F);   // >=0: trunc == floor
      bkt = bkt > 128 ? 128 : bkt;
      o[i] = (m <= n_abs) ? (u8)bkt : (u8)129;
    }
    *(uint4*)(row + c) = *(uint4*)o;
  }
}

// ---------------------------------------------------------------------------
// Attention as dual GEMM: out_pos = pos_s @ V, out_ts = LUT(tsU8) @ V,
// V gathered from proj cols [1024,1536), ragged rows zeroed. Output bf16,
// head-interleaved layout of concat([pos,ts],-1).reshape(.,1024), into ws.
// ---------------------------------------------------------------------------
__global__ __launch_bounds__(256, 1) void attn_gemm(
    const u16* __restrict__ proj,      // T x 1536 bf16
    const int* __restrict__ xoff,      // B+1 (int32)
    const u16* __restrict__ pos_s,     // 1024 x 1024 bf16
    const u8*  __restrict__ tsU8,      // u8 bucket panels
    const float* __restrict__ ts_w,    // 129
    u16* __restrict__ attn_out,        // T x 1024 bf16 (ws)
    int Ttot)
{
  const int flat = blockIdx.x;
  const int nt = 7 - (flat >> 8);          // heavy tiles dispatched first
  const int rem = flat & 255;
  const int b  = rem >> 2;
  const int ct = rem & 3;

  const int off = xoff[b];
  int len = xoff[b + 1] - off;
  if (len < 0) len = 0;
  if (len > 1024) len = 1024;
  if (off < 0 || off + len > Ttot) return;
  const int n0 = nt * 128;
  if (n0 >= len) return;
  const int c0 = ct * 128;
  const int W = 128 * (nt + 1);

  __shared__ u16 lP[128 * 40];
  __shared__ u16 lT[128 * 40];
  __shared__ u16 sV[4096];
  __shared__ float s_tsw[130];

  const int tid = threadIdx.x;
  if (tid < 130) s_tsw[tid] = (tid < 129) ? ts_w[tid] : 0.f;
  __syncthreads();

  const int wave = tid >> 6, lane = tid & 63;
  const int wr = (wave >> 1) * 64, wc = (wave & 1) * 64;
  const int l15 = lane & 15, l4 = lane >> 4;

  f32x4 z = {0.f, 0.f, 0.f, 0.f};
  f32x4 accP[4][4], accT[4][4];
#pragma unroll
  for (int m = 0; m < 4; ++m)
#pragma unroll
    for (int j = 0; j < 4; ++j) { accP[m][j] = z; accT[m][j] = z; }

  const int ar = tid >> 1, ak = (tid & 1) * 16;
  const u16* pRow = pos_s + (size_t)(n0 + ar) * 1024 + ak;
  const u8*  tRow = tsU8 + ts_base_u8(b, nt) + (size_t)ar * W + ak;
  const int vk = tid >> 3, vc = (tid & 7) * 16;

  const int mEnd = (n0 + 128 < len) ? (n0 + 128) : len;

  for (int m0 = 0; m0 < mEnd; m0 += 32) {
    // ---- stage V tile (32 x 128), transposed+swizzled, ragged-zeroed ----
    {
      int mm = m0 + vk;
      uint4 v0 = make_uint4(0, 0, 0, 0), v1 = v0;
      if (mm < len) {
        const u16* src = proj + (size_t)(off + mm) * 1536 + 1024 + c0 + vc;
        v0 = *(const uint4*)src;
        v1 = *(const uint4*)(src + 8);
      }
      u16 tmp[16];
      *(uint4*)tmp       = v0;
      *(uint4*)(tmp + 8) = v1;
      const int kb = vk >> 3, ke = vk & 7;
#pragma unroll
      for (int i = 0; i < 16; ++i) {
        int col = vc + i;
        int o2 = (kb * 2048 + col * 16 + ke * 2) ^ (((col >> 3) & 7) << 4);
        *(u16*)((char*)sV + o2) = tmp[i];
      }
    }
    // ---- stage score tiles: pos streamed bf16; ts via u8 + LDS LUT ----
    {
      uint4 p0 = *(const uint4*)(pRow + m0);
      uint4 p1 = *(const uint4*)(pRow + m0 + 8);
      uint4 tb = *(const uint4*)(tRow + m0);
      u16 tt[16];
      const u8* bp = (const u8*)&tb;
#pragma unroll
      for (int i = 0; i < 16; ++i) tt[i] = f2b(s_tsw[bp[i]]);
      int wb = ar * 40 + ak;
      *(uint4*)&lP[wb]     = p0;
      *(uint4*)&lP[wb + 8] = p1;
      *(uint4*)&lT[wb]     = *(uint4*)tt;
      *(uint4*)&lT[wb + 8] = *(uint4*)(tt + 8);
    }
    __syncthreads();

    bf16x8 ap[4], at[4], bv[4];
#pragma unroll
    for (int m = 0; m < 4; ++m) {
      ap[m] = as_frag(*(const uint4*)&lP[(wr + m * 16 + l15) * 40 + l4 * 8]);
      at[m] = as_frag(*(const uint4*)&lT[(wr + m * 16 + l15) * 40 + l4 * 8]);
    }
#pragma unroll
    for (int j = 0; j < 4; ++j) {
      int col = wc + j * 16 + l15;
      int o2 = (l4 * 2048 + col * 16) ^ (((col >> 3) & 7) << 4);
      bv[j] = as_frag(*(const uint4*)((char*)sV + o2));
    }
#pragma unroll
    for (int m = 0; m < 4; ++m)
#pragma unroll
      for (int j = 0; j < 4; ++j) {
        accP[m][j] = __builtin_amdgcn_mfma_f32_16x16x32_bf16(ap[m], bv[j], accP[m][j], 0, 0, 0);
        accT[m][j] = __builtin_amdgcn_mfma_f32_16x16x32_bf16(at[m], bv[j], accT[m][j], 0, 0, 0);
      }
    __syncthreads();
  }

  // ---- store bf16 with head-interleaved combined layout ----
#pragma unroll
  for (int m = 0; m < 4; ++m)
#pragma unroll
    for (int r = 0; r < 4; ++r) {
      int n = n0 + wr + m * 16 + l4 * 4 + r;
      if (n >= len) continue;
      size_t t = (size_t)(off + n);
#pragma unroll
      for (int j = 0; j < 4; ++j) {
        int hd = c0 + wc + j * 16 + l15;            // 0..511
        int colP = ((hd >> 6) << 7) + (hd & 63);    // h*128 + d
        attn_out[t * 1024 + colP]      = f2b(accP[m][j][r]);
        attn_out[t * 1024 + colP + 64] = f2b(accT[m][j][r]);
      }
    }
}

// ---------------------------------------------------------------------------
// Per-row inv-rms: inv[row] = rsqrt(mean(row^2) + eps). 4 rows/block (1/wave).
// ---------------------------------------------------------------------------
template <int D, bool F32IN>
__global__ __launch_bounds__(256) void row_ss(
    const void* __restrict__ in, float* __restrict__ inv, int T)
{
  const int row = blockIdx.x * 4 + (threadIdx.x >> 6);
  const int lane = threadIdx.x & 63;
  if (row >= T) return;
  float ss = 0.f;
  if constexpr (F32IN) {
    const float* r = (const float*)in + (size_t)row * D;
#pragma unroll
    for (int i = lane * 4; i < D; i += 256) {
      float4 v = *(const float4*)(r + i);
      ss += v.x * v.x + v.y * v.y + v.z * v.z + v.w * v.w;
    }
  } else {
    const u16* r = (const u16*)in + (size_t)row * D;
#pragma unroll
    for (int i = lane * 8; i < D; i += 512) {
      uint4 v = *(const uint4*)(r + i);
      const u16* q = (const u16*)&v;
#pragma unroll
      for (int k = 0; k < 8; ++k) { float f = b2f(q[k]); ss += f * f; }
    }
  }
#pragma unroll
  for (int o = 32; o > 0; o >>= 1) ss += __shfl_down(ss, o, 64);
  if (lane == 0) inv[row] = rsqrtf(ss / (float)D + 1e-6f);
}

// ---------------------------------------------------------------------------
extern "C" void kernel_launch(void* const* d_in, const int* in_sizes, int n_in,
                              void* d_out, int out_size, void* d_ws, size_t ws_size,
                              hipStream_t stream)
{
  const float* x      = (const float*)d_in[0];
  const int*   xoff   = (const int*)d_in[1];    // int32 per harness contract
  const int*   tstamp = (const int*)d_in[2];    // int32 per harness contract
  // d_in[3] = invalid_attn_mask (tril) -- implied by causal masking, unused
  const float* uv     = (const float*)d_in[4];
  const float* pos_w  = (const float*)d_in[5];
  const float* ts_w   = (const float*)d_in[6];
  const float* w_ams  = (const float*)d_in[7];
  const float* w1     = (const float*)d_in[8];
  const float* w2     = (const float*)d_in[9];
  const int T = in_sizes[0] / 512;

  char* ws = (char*)d_ws;
  size_t o = 0;
  auto take = [&](size_t bytes) { size_t r = o; o += (bytes + 255) & ~(size_t)255; return r; };

  // --- static small buffers ---
  u16* uvb    = (u16*)(ws + take((size_t)512 * 1536 * 2));
  u16* wamsb  = (u16*)(ws + take((size_t)1024 * 512 * 2));
  u16* w1b    = (u16*)(ws + take((size_t)512 * 2048 * 2));
  u16* w2b    = (u16*)(ws + take((size_t)2048 * 512 * 2));
  u16* posS   = (u16*)(ws + take((size_t)1024 * 1024 * 2));   // 2 MB

  // --- main regions ---
  size_t o_ts   = take((size_t)64 * 589824);       // tsU8 37.7 MB [ts->attn]
  size_t o_attn = take((size_t)T * 1024 * 2);      // attn bf16 83.9 [attn->F]
  size_t o_proj = take((size_t)T * 1536 * 2);      // proj 125.8 [B->F]
  float* invX = (float*)(ws + take((size_t)T * 4));
  float* invA = (float*)(ws + take((size_t)T * 4));
  float* invH = (float*)(ws + take((size_t)T * 4));

  u8*  tsU8  = (u8*)(ws + o_ts);
  u16* attnS = (u16*)(ws + o_attn);
  u16* proj  = (u16*)(ws + o_proj);
  u16* mid   = (u16*)(ws + o_ts);     // T x 2048 bf16 [H->I]; aliases
                                      // tsU8+attnS+proj-head (all dead by H)
  float* h   = (float*)d_out;         // h lives in d_out (F->I), out in-place

  // If the workspace is too small, launch nothing: clean absmax failure.
  if (ws_size < o) return;

  // weight pre-transpose f32 -> bf16 LDS-image panels
  wprep<<<dim3(12, 16), 256, 0, stream>>>(uv,    uvb,   512,  1536);
  wprep<<<dim3(4, 32),  256, 0, stream>>>(w_ams, wamsb, 1024, 512);
  wprep<<<dim3(16, 16), 256, 0, stream>>>(w1,    w1b,   512,  2048);
  wprep<<<dim3(4, 64),  256, 0, stream>>>(w2,    w2b,   2048, 512);

  // score precompute
  pos_scores<<<1024, 128, 0, stream>>>(pos_w, posS);
  ts_buckets<<<512, 256, 0, stream>>>(tstamp, tsU8);

  // invX over x
  row_ss<512, true><<<(T + 3) / 4, 256, 0, stream>>>(x, invX, T);

  // B: proj = silu((x*invX) @ uv)   (T x 1536)
  dim3 g1(12, (T + 127) / 128);
  gemm_bf16<EPI_SILU_BF16, AM_F32S><<<g1, 256, 0, stream>>>(
      nullptr, x, invX, nullptr, 0, uvb, proj, nullptr, T, 1536, 512);

  // attention -> attnS (ws)
  attn_gemm<<<64 * 32, 256, 0, stream>>>(proj, xoff, posS, tsU8, ts_w, attnS, T);

  // invA over attn
  row_ss<1024, false><<<(T + 3) / 4, 256, 0, stream>>>(attnS, invA, T);

  // F: h = x + ((attn*invA*u) @ w_ams)   (T x 512) -> d_out
  dim3 g3(4, (T + 127) / 128);
  gemm_bf16<EPI_ADD_F32, AM_BF16SM><<<g3, 256, 0, stream>>>(
      attnS, nullptr, invA, proj, 1536, wamsb, h, x, T, 512, 1024);

  // invH over h
  row_ss<512, true><<<(T + 3) / 4, 256, 0, stream>>>(h, invH, T);

  // H: mid = silu((h*invH) @ w1)   (T x 2048) -> aliased region
  dim3 g4(16, (T + 127) / 128);
  gemm_bf16<EPI_SILU_BF16, AM_F32S><<<g4, 256, 0, stream>>>(
      nullptr, h, invH, nullptr, 0, w1b, mid, nullptr, T, 2048, 512);

  // I: out = h + mid @ w2   (T x 512), in-place on d_out
  dim3 g5(4, (T + 127) / 128);
  gemm_bf16<EPI_ADD_F32, AM_BF16><<<g5, 256, 0, stream>>>(
      mid, nullptr, nullptr, nullptr, 0, w2b, h, h, T, 512, 2048);
}

// Round 7
// 855.180 us; speedup vs baseline: 2.0081x; 1.0880x over previous
//
#include <hip/hip_runtime.h>
#include <cmath>

// ---------------------------------------------------------------------------
// SemanticFreeFuXiBlock on MI355X (gfx950), bf16 MFMA implementation.
// B=64, N=1024, D=512, H=8, LD=64, HIDDEN=2048, NB=128, T = in_sizes[0]/512.
// Round 7:
//  - GEMM K-loop reverted to round-5's single-buffer 2-barrier structure
//    (the round-6 dbuf pipeline regressed: vmcnt(0) drain at the barrier
//    kills the prefetch; MfmaUtil halved).
//  - XCD-grouped block swizzle: 1-D grid, all col-tiles of a row-tile run
//    consecutively on the SAME XCD -> A-tile L2-resident, W panels
//    L2-resident per XCD. Bijective for any grid size (m204 formula).
//  - Kept from round 6: AMODE A-staging fusions, u8 ts bucket panels,
//    row_ss inv-rms kernels, workspace plan.
// ---------------------------------------------------------------------------

using u16 = unsigned short;
using u8  = unsigned char;

typedef __bf16 bf16x8 __attribute__((ext_vector_type(8)));
typedef float  f32x4  __attribute__((ext_vector_type(4)));

#define TS_SCALE_F (float)(128.0 / 14.0)

__device__ __forceinline__ u16 f2b(float f) {            // RNE f32 -> bf16 bits
  unsigned u = __float_as_uint(f);
  unsigned r = 0x7FFFu + ((u >> 16) & 1u);
  return (u16)((u + r) >> 16);
}
__device__ __forceinline__ float b2f(u16 v) {
  return __uint_as_float(((unsigned)v) << 16);
}
__device__ __forceinline__ bf16x8 as_frag(uint4 r) {
  union { uint4 u; bf16x8 v; } c; c.u = r; return c.v;
}

// async global->LDS, 16 bytes per lane (lds dest: wave base + lane*16)
__device__ __forceinline__ void gload_lds16(const u16* g, u16* l) {
  __builtin_amdgcn_global_load_lds(
      (const __attribute__((address_space(1))) unsigned int*)g,
      (__attribute__((address_space(3))) unsigned int*)l, 16, 0, 0);
}

// ts u8 panel base (bytes): per batch 589824; per nt prefix nt*(nt+1)/2*16384.
__device__ __forceinline__ size_t ts_base_u8(int b, int nt) {
  return (size_t)b * 589824 + (size_t)(nt * (nt + 1) / 2) * 16384;
}

// ---------------------------------------------------------------------------
// Weight pre-transpose: W (KxN f32 row-major) -> Wp bf16 panels.
// Wp elem offset = ((p*(K/32)+s)*4 + kb)*1024 + c*8 + ke
//   holds W[s*32 + kb*8 + ke][p*128 + c].
// ---------------------------------------------------------------------------
__global__ __launch_bounds__(256) void wprep(
    const float* __restrict__ W, u16* __restrict__ Wp, int K, int N)
{
  const int p = blockIdx.x, s = blockIdx.y;
  const int t = threadIdx.x;
  size_t base = ((size_t)p * (K >> 5) + s) * 4096;
  const int e0 = t * 16;
  u16 o[16];
#pragma unroll
  for (int i = 0; i < 16; ++i) {
    int e = e0 + i;
    int kb = e >> 10, r = e & 1023, c = r >> 3, ke = r & 7;
    o[i] = f2b(W[(size_t)(s * 32 + kb * 8 + ke) * N + p * 128 + c]);
  }
  *(uint4*)(Wp + base + e0)     = *(uint4*)o;
  *(uint4*)(Wp + base + e0 + 8) = *(uint4*)(o + 8);
}

// ---------------------------------------------------------------------------
// Generic bf16 GEMM: C = epi(Asrc @ W), W pre-transposed to LDS image.
// Tile 128x128x32, 256 thr = 4 waves (2x2 of 64x64). Single-buffer 2-barrier
// K-loop. 1-D grid with XCD-grouped swizzle: work = row-major (row, col),
// all ncb col-tiles of a row-tile consecutive on one XCD.
// AMODE: 0 = bf16 A; 1 = f32 A * inv[row]; 2 = bf16 A * inv[row] * bf16 U.
// ---------------------------------------------------------------------------
#define EPI_SILU_BF16 0
#define EPI_ADD_F32   1
#define AM_BF16   0
#define AM_F32S   1
#define AM_BF16SM 2

template <int EPI, int AMODE>
__global__ __launch_bounds__(256, 2) void gemm_bf16(
    const u16* __restrict__ A, const float* __restrict__ Af,
    const float* __restrict__ inv, const u16* __restrict__ U, int ustride,
    const u16* __restrict__ Wp, void* __restrict__ C,
    const float* __restrict__ ADD, int M, int N, int K, int ncb)
{
  __shared__ u16 lA[128 * 40];
  __shared__ u16 lB[4096];

  // --- XCD-grouped bijective swizzle (m204): xcd k gets work chunk
  //     [k*q + min(k,r), ...) of size q + (k<r); within a chunk, work is
  //     row-major so col-tiles of a row-tile are adjacent in time. ---
  const int nblk = gridDim.x;
  const int q = nblk >> 3, r = nblk & 7;
  const int xcd = blockIdx.x & 7, li = blockIdx.x >> 3;
  const int work = xcd * q + (xcd < r ? xcd : r) + li;
  const int c0b = work % ncb;
  const int t0  = (work / ncb) * 128;
  const int c0  = c0b * 128;

  const int tid  = threadIdx.x;
  const int wave = tid >> 6, lane = tid & 63;
  const int wr   = (wave >> 1) * 64, wc = (wave & 1) * 64;
  const int l15  = lane & 15, l4 = lane >> 4;

  f32x4 z = {0.f, 0.f, 0.f, 0.f};
  f32x4 acc[4][4];
#pragma unroll
  for (int m = 0; m < 4; ++m)
#pragma unroll
    for (int j = 0; j < 4; ++j) acc[m][j] = z;

  const int ar = tid >> 1, ak = (tid & 1) * 16;      // A stage: 16 elems along K
  const int row = t0 + ar;
  const bool arow_ok = row < M;
  float rinv = 0.f;
  if (AMODE != AM_BF16 && arow_ok) rinv = inv[row];
  const u16*   ab = (AMODE != AM_F32S) ? A + (size_t)row * K + ak : nullptr;
  const float* af = (AMODE == AM_F32S) ? Af + (size_t)row * K + ak : nullptr;
  const u16*   um = (AMODE == AM_BF16SM) ? U + (size_t)row * ustride + ak : nullptr;

  const int ksteps = K >> 5;
  const u16* wsrc = Wp + (size_t)c0b * ksteps * 4096 + wave * 1024 + lane * 8;
  u16* ldsb = &lB[wave * 1024];

  for (int s = 0; s < ksteps; ++s) {
    const int k0 = s * 32;
    uint4 pr[4];
    const uint4 z4 = make_uint4(0, 0, 0, 0);
    if (!arow_ok) { pr[0] = z4; pr[1] = z4; pr[2] = z4; pr[3] = z4; }
    else if constexpr (AMODE == AM_BF16) {
      pr[0] = *(const uint4*)(ab + k0);
      pr[1] = *(const uint4*)(ab + k0 + 8);
    } else if constexpr (AMODE == AM_F32S) {
      pr[0] = *(const uint4*)(af + k0);
      pr[1] = *(const uint4*)(af + k0 + 4);
      pr[2] = *(const uint4*)(af + k0 + 8);
      pr[3] = *(const uint4*)(af + k0 + 12);
    } else {
      pr[0] = *(const uint4*)(ab + k0);
      pr[1] = *(const uint4*)(ab + k0 + 8);
      pr[2] = *(const uint4*)(um + k0);
      pr[3] = *(const uint4*)(um + k0 + 8);
    }
    // B: async DMA, 2 x 1KB per wave
    gload_lds16(wsrc,       ldsb);
    gload_lds16(wsrc + 512, ldsb + 512);
    wsrc += 4096;
    // A: transform + vector LDS write into padded rows
    {
      u16 tmp[16];
      if constexpr (AMODE == AM_BF16) {
        *(uint4*)tmp       = pr[0];
        *(uint4*)(tmp + 8) = pr[1];
      } else if constexpr (AMODE == AM_F32S) {
        const float* f = (const float*)pr;
#pragma unroll
        for (int i = 0; i < 16; ++i) tmp[i] = f2b(f[i] * rinv);
      } else {
        const u16* a = (const u16*)pr;
        const u16* u = (const u16*)(pr + 2);
#pragma unroll
        for (int i = 0; i < 16; ++i) tmp[i] = f2b(b2f(a[i]) * rinv * b2f(u[i]));
      }
      *(uint4*)&lA[ar * 40 + ak]     = *(uint4*)tmp;
      *(uint4*)&lA[ar * 40 + ak + 8] = *(uint4*)(tmp + 8);
    }
    __syncthreads();

    bf16x8 afr[4], bfv[4];
#pragma unroll
    for (int m = 0; m < 4; ++m)
      afr[m] = as_frag(*(const uint4*)&lA[(wr + m * 16 + l15) * 40 + l4 * 8]);
#pragma unroll
    for (int j = 0; j < 4; ++j)
      bfv[j] = as_frag(*(const uint4*)&lB[(l4 << 10) + (wc + j * 16 + l15) * 8]);
#pragma unroll
    for (int m = 0; m < 4; ++m)
#pragma unroll
      for (int j = 0; j < 4; ++j)
        acc[m][j] = __builtin_amdgcn_mfma_f32_16x16x32_bf16(afr[m], bfv[j], acc[m][j], 0, 0, 0);
    __syncthreads();
  }

#pragma unroll
  for (int m = 0; m < 4; ++m) {
#pragma unroll
    for (int rr = 0; rr < 4; ++rr) {
      int orow = t0 + wr + m * 16 + l4 * 4 + rr;
      if (orow >= M) continue;
#pragma unroll
      for (int j = 0; j < 4; ++j) {
        int col = c0 + wc + j * 16 + l15;
        size_t idx = (size_t)orow * N + col;
        float y = acc[m][j][rr];
        if constexpr (EPI == EPI_SILU_BF16) {
          float s = y / (1.f + __expf(-y));          // silu
          ((u16*)C)[idx] = f2b(s);
        } else {
          ((float*)C)[idx] = y + ADD[idx];
        }
      }
    }
  }
}

// ---------------------------------------------------------------------------
// pos score table: pos_s[n][m] = pos_w[n-m+1023] * (m<=n), bf16, 1024x1024.
// ---------------------------------------------------------------------------
__global__ __launch_bounds__(128) void pos_scores(
    const float* __restrict__ pos_w, u16* __restrict__ pos_s)
{
  const int n = blockIdx.x;
  const int m0 = threadIdx.x * 8;
  u16 o[8];
#pragma unroll
  for (int i = 0; i < 8; ++i) {
    int m = m0 + i;
    float v = (m <= n) ? pos_w[n - m + 1023] : 0.f;
    o[i] = f2b(v);
  }
  *(uint4*)(pos_s + (size_t)n * 1024 + m0) = *(uint4*)o;
}

// ---------------------------------------------------------------------------
// ts bucket panels (u8): for (b, nt), 128 rows x W cols, W = 128*(nt+1):
//   bucket = clip(floor(log1p|dt|*SCALE),0,128); masked (m>n) -> 129.
// ---------------------------------------------------------------------------
__global__ __launch_bounds__(256) void ts_buckets(
    const int* __restrict__ tstamp, u8* __restrict__ ts_s)
{
  const int nt = 7 - (blockIdx.x >> 6);
  const int b  = blockIdx.x & 63;
  const int W  = 128 * (nt + 1);
  const int n0 = nt * 128;
  const int tid = threadIdx.x;

  __shared__ int tsm[1024];
  for (int i = tid; i < W; i += 256) tsm[i] = tstamp[b * 1024 + i];
  __syncthreads();

  const int r = tid >> 1, h = tid & 1;
  const int n_abs = n0 + r;
  const int t_n = tstamp[b * 1024 + n_abs];
  const int half = W >> 1;
  const int c0 = h * half;
  u8* row = ts_s + ts_base_u8(b, nt) + (size_t)r * W + c0;

  for (int c = 0; c < half; c += 16) {
    u8 o[16];
#pragma unroll
    for (int i = 0; i < 16; ++i) {
      int m = c0 + c + i;
      int d = t_n - tsm[m];
      if (d < 0) d = -d;
      int bkt = (int)(log1pf((float)d) * TS_SCALE_F);   // >=0: trunc == floor
      bkt = bkt > 128 ? 128 : bkt;
      o[i] = (m <= n_abs) ? (u8)bkt : (u8)129;
    }
    *(uint4*)(row + c) = *(uint4*)o;
  }
}

// ---------------------------------------------------------------------------
// Attention as dual GEMM: out_pos = pos_s @ V, out_ts = LUT(tsU8) @ V,
// V gathered from proj cols [1024,1536), ragged rows zeroed. Output bf16,
// head-interleaved layout of concat([pos,ts],-1).reshape(.,1024), into ws.
// ---------------------------------------------------------------------------
__global__ __launch_bounds__(256, 1) void attn_gemm(
    const u16* __restrict__ proj,      // T x 1536 bf16
    const int* __restrict__ xoff,      // B+1 (int32)
    const u16* __restrict__ pos_s,     // 1024 x 1024 bf16
    const u8*  __restrict__ tsU8,      // u8 bucket panels
    const float* __restrict__ ts_w,    // 129
    u16* __restrict__ attn_out,        // T x 1024 bf16 (ws)
    int Ttot)
{
  const int flat = blockIdx.x;
  const int nt = 7 - (flat >> 8);          // heavy tiles dispatched first
  const int rem = flat & 255;
  const int b  = rem >> 2;
  const int ct = rem & 3;

  const int off = xoff[b];
  int len = xoff[b + 1] - off;
  if (len < 0) len = 0;
  if (len > 1024) len = 1024;
  if (off < 0 || off + len > Ttot) return;
  const int n0 = nt * 128;
  if (n0 >= len) return;
  const int c0 = ct * 128;
  const int W = 128 * (nt + 1);

  __shared__ u16 lP[128 * 40];
  __shared__ u16 lT[128 * 40];
  __shared__ u16 sV[4096];
  __shared__ float s_tsw[130];

  const int tid = threadIdx.x;
  if (tid < 130) s_tsw[tid] = (tid < 129) ? ts_w[tid] : 0.f;
  __syncthreads();

  const int wave = tid >> 6, lane = tid & 63;
  const int wr = (wave >> 1) * 64, wc = (wave & 1) * 64;
  const int l15 = lane & 15, l4 = lane >> 4;

  f32x4 z = {0.f, 0.f, 0.f, 0.f};
  f32x4 accP[4][4], accT[4][4];
#pragma unroll
  for (int m = 0; m < 4; ++m)
#pragma unroll
    for (int j = 0; j < 4; ++j) { accP[m][j] = z; accT[m][j] = z; }

  const int ar = tid >> 1, ak = (tid & 1) * 16;
  const u16* pRow = pos_s + (size_t)(n0 + ar) * 1024 + ak;
  const u8*  tRow = tsU8 + ts_base_u8(b, nt) + (size_t)ar * W + ak;
  const int vk = tid >> 3, vc = (tid & 7) * 16;

  const int mEnd = (n0 + 128 < len) ? (n0 + 128) : len;

  for (int m0 = 0; m0 < mEnd; m0 += 32) {
    // ---- stage V tile (32 x 128), transposed+swizzled, ragged-zeroed ----
    {
      int mm = m0 + vk;
      uint4 v0 = make_uint4(0, 0, 0, 0), v1 = v0;
      if (mm < len) {
        const u16* src = proj + (size_t)(off + mm) * 1536 + 1024 + c0 + vc;
        v0 = *(const uint4*)src;
        v1 = *(const uint4*)(src + 8);
      }
      u16 tmp[16];
      *(uint4*)tmp       = v0;
      *(uint4*)(tmp + 8) = v1;
      const int kb = vk >> 3, ke = vk & 7;
#pragma unroll
      for (int i = 0; i < 16; ++i) {
        int col = vc + i;
        int o2 = (kb * 2048 + col * 16 + ke * 2) ^ (((col >> 3) & 7) << 4);
        *(u16*)((char*)sV + o2) = tmp[i];
      }
    }
    // ---- stage score tiles: pos streamed bf16; ts via u8 + LDS LUT ----
    {
      uint4 p0 = *(const uint4*)(pRow + m0);
      uint4 p1 = *(const uint4*)(pRow + m0 + 8);
      uint4 tb = *(const uint4*)(tRow + m0);
      u16 tt[16];
      const u8* bp = (const u8*)&tb;
#pragma unroll
      for (int i = 0; i < 16; ++i) tt[i] = f2b(s_tsw[bp[i]]);
      int wb = ar * 40 + ak;
      *(uint4*)&lP[wb]     = p0;
      *(uint4*)&lP[wb + 8] = p1;
      *(uint4*)&lT[wb]     = *(uint4*)tt;
      *(uint4*)&lT[wb + 8] = *(uint4*)(tt + 8);
    }
    __syncthreads();

    bf16x8 ap[4], at[4], bv[4];
#pragma unroll
    for (int m = 0; m < 4; ++m) {
      ap[m] = as_frag(*(const uint4*)&lP[(wr + m * 16 + l15) * 40 + l4 * 8]);
      at[m] = as_frag(*(const uint4*)&lT[(wr + m * 16 + l15) * 40 + l4 * 8]);
    }
#pragma unroll
    for (int j = 0; j < 4; ++j) {
      int col = wc + j * 16 + l15;
      int o2 = (l4 * 2048 + col * 16) ^ (((col >> 3) & 7) << 4);
      bv[j] = as_frag(*(const uint4*)((char*)sV + o2));
    }
#pragma unroll
    for (int m = 0; m < 4; ++m)
#pragma unroll
      for (int j = 0; j < 4; ++j) {
        accP[m][j] = __builtin_amdgcn_mfma_f32_16x16x32_bf16(ap[m], bv[j], accP[m][j], 0, 0, 0);
        accT[m][j] = __builtin_amdgcn_mfma_f32_16x16x32_bf16(at[m], bv[j], accT[m][j], 0, 0, 0);
      }
    __syncthreads();
  }

  // ---- store bf16 with head-interleaved combined layout ----
#pragma unroll
  for (int m = 0; m < 4; ++m)
#pragma unroll
    for (int r = 0; r < 4; ++r) {
      int n = n0 + wr + m * 16 + l4 * 4 + r;
      if (n >= len) continue;
      size_t t = (size_t)(off + n);
#pragma unroll
      for (int j = 0; j < 4; ++j) {
        int hd = c0 + wc + j * 16 + l15;            // 0..511
        int colP = ((hd >> 6) << 7) + (hd & 63);    // h*128 + d
        attn_out[t * 1024 + colP]      = f2b(accP[m][j][r]);
        attn_out[t * 1024 + colP + 64] = f2b(accT[m][j][r]);
      }
    }
}

// ---------------------------------------------------------------------------
// Per-row inv-rms: inv[row] = rsqrt(mean(row^2) + eps). 4 rows/block (1/wave).
// ---------------------------------------------------------------------------
template <int D, bool F32IN>
__global__ __launch_bounds__(256) void row_ss(
    const void* __restrict__ in, float* __restrict__ inv, int T)
{
  const int row = blockIdx.x * 4 + (threadIdx.x >> 6);
  const int lane = threadIdx.x & 63;
  if (row >= T) return;
  float ss = 0.f;
  if constexpr (F32IN) {
    const float* r = (const float*)in + (size_t)row * D;
#pragma unroll
    for (int i = lane * 4; i < D; i += 256) {
      float4 v = *(const float4*)(r + i);
      ss += v.x * v.x + v.y * v.y + v.z * v.z + v.w * v.w;
    }
  } else {
    const u16* r = (const u16*)in + (size_t)row * D;
#pragma unroll
    for (int i = lane * 8; i < D; i += 512) {
      uint4 v = *(const uint4*)(r + i);
      const u16* q = (const u16*)&v;
#pragma unroll
      for (int k = 0; k < 8; ++k) { float f = b2f(q[k]); ss += f * f; }
    }
  }
#pragma unroll
  for (int o = 32; o > 0; o >>= 1) ss += __shfl_down(ss, o, 64);
  if (lane == 0) inv[row] = rsqrtf(ss / (float)D + 1e-6f);
}

// ---------------------------------------------------------------------------
extern "C" void kernel_launch(void* const* d_in, const int* in_sizes, int n_in,
                              void* d_out, int out_size, void* d_ws, size_t ws_size,
                              hipStream_t stream)
{
  const float* x      = (const float*)d_in[0];
  const int*   xoff   = (const int*)d_in[1];    // int32 per harness contract
  const int*   tstamp = (const int*)d_in[2];    // int32 per harness contract
  // d_in[3] = invalid_attn_mask (tril) -- implied by causal masking, unused
  const float* uv     = (const float*)d_in[4];
  const float* pos_w  = (const float*)d_in[5];
  const float* ts_w   = (const float*)d_in[6];
  const float* w_ams  = (const float*)d_in[7];
  const float* w1     = (const float*)d_in[8];
  const float* w2     = (const float*)d_in[9];
  const int T = in_sizes[0] / 512;
  const int nrow = (T + 127) / 128;

  char* ws = (char*)d_ws;
  size_t o = 0;
  auto take = [&](size_t bytes) { size_t r = o; o += (bytes + 255) & ~(size_t)255; return r; };

  // --- static small buffers ---
  u16* uvb    = (u16*)(ws + take((size_t)512 * 1536 * 2));
  u16* wamsb  = (u16*)(ws + take((size_t)1024 * 512 * 2));
  u16* w1b    = (u16*)(ws + take((size_t)512 * 2048 * 2));
  u16* w2b    = (u16*)(ws + take((size_t)2048 * 512 * 2));
  u16* posS   = (u16*)(ws + take((size_t)1024 * 1024 * 2));   // 2 MB

  // --- main regions ---
  size_t o_ts   = take((size_t)64 * 589824);       // tsU8 37.7 MB [ts->attn]
  size_t o_attn = take((size_t)T * 1024 * 2);      // attn bf16 83.9 [attn->F]
  size_t o_proj = take((size_t)T * 1536 * 2);      // proj 125.8 [B->F]
  float* invX = (float*)(ws + take((size_t)T * 4));
  float* invA = (float*)(ws + take((size_t)T * 4));
  float* invH = (float*)(ws + take((size_t)T * 4));

  u8*  tsU8  = (u8*)(ws + o_ts);
  u16* attnS = (u16*)(ws + o_attn);
  u16* proj  = (u16*)(ws + o_proj);
  u16* mid   = (u16*)(ws + o_ts);     // T x 2048 bf16 [H->I]; aliases
                                      // tsU8+attnS+proj-head (all dead by H)
  float* h   = (float*)d_out;         // h lives in d_out (F->I), out in-place

  // If the workspace is too small, launch nothing: clean absmax failure.
  if (ws_size < o) return;

  // weight pre-transpose f32 -> bf16 LDS-image panels
  wprep<<<dim3(12, 16), 256, 0, stream>>>(uv,    uvb,   512,  1536);
  wprep<<<dim3(4, 32),  256, 0, stream>>>(w_ams, wamsb, 1024, 512);
  wprep<<<dim3(16, 16), 256, 0, stream>>>(w1,    w1b,   512,  2048);
  wprep<<<dim3(4, 64),  256, 0, stream>>>(w2,    w2b,   2048, 512);

  // score precompute
  pos_scores<<<1024, 128, 0, stream>>>(pos_w, posS);
  ts_buckets<<<512, 256, 0, stream>>>(tstamp, tsU8);

  // invX over x
  row_ss<512, true><<<(T + 3) / 4, 256, 0, stream>>>(x, invX, T);

  // B: proj = silu((x*invX) @ uv)   (T x 1536)
  gemm_bf16<EPI_SILU_BF16, AM_F32S><<<12 * nrow, 256, 0, stream>>>(
      nullptr, x, invX, nullptr, 0, uvb, proj, nullptr, T, 1536, 512, 12);

  // attention -> attnS (ws)
  attn_gemm<<<64 * 32, 256, 0, stream>>>(proj, xoff, posS, tsU8, ts_w, attnS, T);

  // invA over attn
  row_ss<1024, false><<<(T + 3) / 4, 256, 0, stream>>>(attnS, invA, T);

  // F: h = x + ((attn*invA*u) @ w_ams)   (T x 512) -> d_out
  gemm_bf16<EPI_ADD_F32, AM_BF16SM><<<4 * nrow, 256, 0, stream>>>(
      attnS, nullptr, invA, proj, 1536, wamsb, h, x, T, 512, 1024, 4);

  // invH over h
  row_ss<512, true><<<(T + 3) / 4, 256, 0, stream>>>(h, invH, T);

  // H: mid = silu((h*invH) @ w1)   (T x 2048) -> aliased region
  gemm_bf16<EPI_SILU_BF16, AM_F32S><<<16 * nrow, 256, 0, stream>>>(
      nullptr, h, invH, nullptr, 0, w1b, mid, nullptr, T, 2048, 512, 16);

  // I: out = h + mid @ w2   (T x 512), in-place on d_out
  gemm_bf16<EPI_ADD_F32, AM_BF16><<<4 * nrow, 256, 0, stream>>>(
      mid, nullptr, nullptr, nullptr, 0, w2b, h, h, T, 512, 2048, 4);
}